// Round 9
// baseline (515.333 us; speedup 1.0000x reference)
//
#include <hip/hip_runtime.h>

#define EMB 64
#define CH 4096
#define ST 65

// ---------------------------------------------------------------------------
// Round 9: kill the agg64 barrier-straggler (r7/r8 post-mortem: block time =
// max over 64 random node degrees; 1024-thd barrier made it worse).
//  - degree-sorted permutation (counting sort, LDS pre-reserved; ~8us):
//    agg blocks now process equal-degree nodes -> max ~= mean.
//  - agg64: 512 thd / 8 waves (r7 structure) + xt[r][f] stride-65 layout
//    (r8's conflict fix, isolated). Nodes via perm.
//  - per-node arithmetic & adj order unchanged -> bit-identical output.
// ---------------------------------------------------------------------------

static __device__ __forceinline__ unsigned short f2bf(float x) {
    union { float f; unsigned u; } v; v.f = x;
    unsigned r = v.u + 0x7fffu + ((v.u >> 16) & 1u);   // RNE
    return (unsigned short)(r >> 16);
}
static __device__ __forceinline__ float bflo(unsigned w) {
    union { unsigned u; float f; } v; v.u = w << 16; return v.f;
}
static __device__ __forceinline__ float bfhi(unsigned w) {
    union { unsigned u; float f; } v; v.u = w & 0xffff0000u; return v.f;
}

__global__ __launch_bounds__(256) void zero_int_kernel(int* __restrict__ p, int n) {
    int i = blockIdx.x * 256 + threadIdx.x;
    if (i < n) p[i] = 0;
}

__global__ __launch_bounds__(256) void bucket_hist_kernel(
    const int* __restrict__ src, const int* __restrict__ dst, int E,
    int* __restrict__ bkt_cnt_c, int* __restrict__ bkt_cnt_v,
    int shc, int shv, int NBC, int NBV)
{
    __shared__ int hc[512], hv[512];
    int t = threadIdx.x;
    int base = blockIdx.x * CH;
    int n = min(CH, E - base);
    for (int i = t; i < NBC; i += 256) hc[i] = 0;
    for (int i = t; i < NBV; i += 256) hv[i] = 0;
    __syncthreads();
    for (int li = t; li < n; li += 256) {
        atomicAdd(&hc[src[base + li] >> shc], 1);
        atomicAdd(&hv[dst[base + li] >> shv], 1);
    }
    __syncthreads();
    for (int i = t; i < NBC; i += 256) { int c = hc[i]; if (c) atomicAdd(&bkt_cnt_c[i], c); }
    for (int i = t; i < NBV; i += 256) { int c = hv[i]; if (c) atomicAdd(&bkt_cnt_v[i], c); }
}

// one block: exclusive-scan two count arrays in place (n<=512 each)
__global__ __launch_bounds__(256) void scan_buckets_kernel(
    int* __restrict__ bc, int nbc, int* __restrict__ bv, int nbv, int E)
{
    __shared__ int sc[256];
    int t = threadIdx.x;
    {
        int v0 = (2 * t < nbc) ? bc[2 * t] : 0;
        int v1 = (2 * t + 1 < nbc) ? bc[2 * t + 1] : 0;
        sc[t] = v0 + v1;
        __syncthreads();
        for (int off = 1; off < 256; off <<= 1) {
            int x = (t >= off) ? sc[t - off] : 0;
            __syncthreads();
            sc[t] += x;
            __syncthreads();
        }
        int ex = (t > 0) ? sc[t - 1] : 0;
        if (2 * t < nbc) bc[2 * t] = ex;
        if (2 * t + 1 < nbc) bc[2 * t + 1] = ex + v0;
        if (t == 0) bc[nbc] = E;
        __syncthreads();
    }
    {
        int v0 = (2 * t < nbv) ? bv[2 * t] : 0;
        int v1 = (2 * t + 1 < nbv) ? bv[2 * t + 1] : 0;
        sc[t] = v0 + v1;
        __syncthreads();
        for (int off = 1; off < 256; off <<= 1) {
            int x = (t >= off) ? sc[t - off] : 0;
            __syncthreads();
            sc[t] += x;
            __syncthreads();
        }
        int ex = (t > 0) ? sc[t - 1] : 0;
        if (2 * t < nbv) bv[2 * t] = ex;
        if (2 * t + 1 < nbv) bv[2 * t + 1] = ex + v0;
        if (t == 0) bv[nbv] = E;
    }
}

// Phase 1: per-chunk LDS binning; packed u32 {local_node<<23 | other}.
__global__ __launch_bounds__(256) void bin_edges_kernel(
    const int* __restrict__ src, const int* __restrict__ dst, int E,
    const int* __restrict__ bb_c, const int* __restrict__ bb_v,
    int* __restrict__ gcur_c, int* __restrict__ gcur_v,
    unsigned* __restrict__ tmp_c, unsigned* __restrict__ tmp_v,
    int shc, int shv, int NBC, int NBV)
{
    __shared__ int hc[512], hv[512];
    int t = threadIdx.x;
    int base = blockIdx.x * CH;
    int n = min(CH, E - base);
    unsigned mc = (1u << shc) - 1u, mv = (1u << shv) - 1u;

    for (int i = t; i < NBC; i += 256) hc[i] = 0;
    for (int i = t; i < NBV; i += 256) hv[i] = 0;
    __syncthreads();

    int ss[16], dd[16];
#pragma unroll
    for (int q = 0; q < 16; ++q) {
        int li = t + q * 256;
        bool ok = li < n;
        ss[q] = ok ? src[base + li] : -1;
        dd[q] = ok ? dst[base + li] : -1;
        if (ok) {
            atomicAdd(&hc[ss[q] >> shc], 1);
            atomicAdd(&hv[dd[q] >> shv], 1);
        }
    }
    __syncthreads();

    for (int i = t; i < NBC; i += 256) {
        int c = hc[i];
        hc[i] = c ? (bb_c[i] + atomicAdd(&gcur_c[i], c)) : 0;
    }
    for (int i = t; i < NBV; i += 256) {
        int c = hv[i];
        hv[i] = c ? (bb_v[i] + atomicAdd(&gcur_v[i], c)) : 0;
    }
    __syncthreads();

#pragma unroll
    for (int q = 0; q < 16; ++q) {
        int li = t + q * 256;
        if (li < n) {
            unsigned s = (unsigned)ss[q], d = (unsigned)dd[q];
            int pc = atomicAdd(&hc[s >> shc], 1);
            tmp_c[pc] = ((s & mc) << 23) | d;
            int pv = atomicAdd(&hv[d >> shv], 1);
            tmp_v[pv] = ((d & mv) << 23) | s;
        }
    }
}

// Phase 2: wg-per-bucket. LDS per-node hist -> scan -> rp; rank -> adj.
__global__ __launch_bounds__(256) void regroup2_kernel(
    const unsigned* __restrict__ tmp, const int* __restrict__ bb,
    int* __restrict__ rp, int* __restrict__ adj, int n_nodes, int sh, int E, int nb)
{
    __shared__ int cnt[512];
    __shared__ int offs[512];
    __shared__ int sc[256];
    int t = threadIdx.x;
    int b = blockIdx.x;
    int node0 = b << sh;
    int node1 = min(node0 + (1 << sh), n_nodes);
    int nn = node1 - node0;
    for (int i = t; i < nn; i += 256) cnt[i] = 0;
    __syncthreads();
    int beg = bb[b], end = bb[b + 1];
    for (int e = beg + t; e < end; e += 256)
        atomicAdd(&cnt[tmp[e] >> 23], 1);
    __syncthreads();
    int v0 = (2 * t < nn) ? cnt[2 * t] : 0;
    int v1 = (2 * t + 1 < nn) ? cnt[2 * t + 1] : 0;
    sc[t] = v0 + v1;
    __syncthreads();
    for (int off = 1; off < 256; off <<= 1) {
        int x = (t >= off) ? sc[t - off] : 0;
        __syncthreads();
        sc[t] += x;
        __syncthreads();
    }
    int ex = (t > 0) ? sc[t - 1] : 0;
    if (2 * t < nn) offs[2 * t] = ex;
    if (2 * t + 1 < nn) offs[2 * t + 1] = ex + v0;
    __syncthreads();
    for (int i = t; i < nn; i += 256) {
        rp[node0 + i] = beg + offs[i];
        cnt[i] = 0;
    }
    if (b == nb - 1 && t == 0) rp[n_nodes] = E;
    __syncthreads();
    for (int e = beg + t; e < end; e += 256) {
        unsigned p = tmp[e];
        int d = (int)(p >> 23);
        int r = atomicAdd(&cnt[d], 1);
        adj[beg + offs[d] + r] = (int)(p & 0x7fffffu);
    }
}

// degree histogram (clamped at 511), LDS-preaggregated
__global__ __launch_bounds__(256) void deg_hist_kernel(
    const int* __restrict__ rp, int n, int* __restrict__ gbins)
{
    __shared__ int h[512];
    int t = threadIdx.x;
    for (int i = t; i < 512; i += 256) h[i] = 0;
    __syncthreads();
    int base = blockIdx.x * 2048;
#pragma unroll
    for (int q = 0; q < 8; ++q) {
        int i = base + t + q * 256;
        if (i < n) {
            int deg = min(rp[i + 1] - rp[i], 511);
            atomicAdd(&h[deg], 1);
        }
    }
    __syncthreads();
    for (int i = t; i < 512; i += 256) { int c = h[i]; if (c) atomicAdd(&gbins[i], c); }
}

// counting-sort scatter with per-block LDS run reservation
__global__ __launch_bounds__(256) void deg_scatter_kernel(
    const int* __restrict__ rp, int n, const int* __restrict__ bases,
    int* __restrict__ cur, int* __restrict__ perm)
{
    __shared__ int h[512];
    __shared__ int rb[512];
    int t = threadIdx.x;
    for (int i = t; i < 512; i += 256) h[i] = 0;
    __syncthreads();
    int base = blockIdx.x * 2048;
    int dg[8];
#pragma unroll
    for (int q = 0; q < 8; ++q) {
        int i = base + t + q * 256;
        dg[q] = -1;
        if (i < n) {
            dg[q] = min(rp[i + 1] - rp[i], 511);
            atomicAdd(&h[dg[q]], 1);
        }
    }
    __syncthreads();
    for (int i = t; i < 512; i += 256) {
        int c = h[i];
        rb[i] = c ? (bases[i] + atomicAdd(&cur[i], c)) : 0;
        h[i] = 0;
    }
    __syncthreads();
#pragma unroll
    for (int q = 0; q < 8; ++q) {
        int i = base + t + q * 256;
        if (i < n) {
            int r = atomicAdd(&h[dg[q]], 1);
            perm[rb[dg[q]] + r] = i;
        }
    }
}

// Fully fused node pipeline:
//   xhat = relu(relu(((x+shift)*scale)@W1+b1)@W2+b2)   (LDS only)
//   tb   = bf16(xhat @ Wll)      (layer-0 gather table)
//   u    = xhat @ Wlr            (layer-0 self term, f32)
template <int NF>
__global__ __launch_bounds__(256) void embed_fused_kernel(
    const float* __restrict__ x, const float* __restrict__ shift, const float* __restrict__ scale,
    const float* __restrict__ w1, const float* __restrict__ b1,
    const float* __restrict__ w2, const float* __restrict__ b2,
    const float* __restrict__ wll, const float* __restrict__ wlr,
    unsigned short* __restrict__ tb, float* __restrict__ u, int n)
{
    __shared__ float xs[NF * 68];
    __shared__ float w1s[NF * EMB];
    __shared__ float hs[EMB * 68];    // h, then xhat (transposed [k][r])
    __shared__ float ws[EMB * EMB];   // w2 -> wll -> wlr
    __shared__ float b1s[EMB], b2s[EMB];

    int t = threadIdx.x;
    long row0 = (long)blockIdx.x * 64;
    int nrow = (int)((n - row0 < 64) ? (n - row0) : 64);

    for (int i = t; i < NF * EMB; i += 256) w1s[i] = w1[i];
    if (t < EMB) { b1s[t] = b1[t]; b2s[t] = b2[t]; }
    {
        const float4* wg = (const float4*)w2;
        float4* wl = (float4*)ws;
#pragma unroll
        for (int q = 0; q < 4; ++q) wl[t + q * 256] = wg[t + q * 256];
    }
    for (int i = t; i < 64 * NF; i += 256) {
        int r = i / NF, k = i - r * NF;
        float v = (r < nrow) ? x[row0 * NF + i] : 0.f;
        xs[k * 68 + r] = (v + shift[k]) * scale[k];
    }
    __syncthreads();

    int r0 = (t >> 4) * 4;
    int c0 = (t & 15) * 4;

    // GEMM1: h = relu(xs @ W1 + b1), stored transposed into hs
    {
        float a1[4][4] = {{0.f}};
#pragma unroll
        for (int k = 0; k < NF; ++k) {
            float4 xv = *(const float4*)&xs[k * 68 + r0];
            float4 wv = *(const float4*)&w1s[k * EMB + c0];
            float xa[4] = {xv.x, xv.y, xv.z, xv.w};
            float wa[4] = {wv.x, wv.y, wv.z, wv.w};
#pragma unroll
            for (int i = 0; i < 4; ++i)
#pragma unroll
                for (int j = 0; j < 4; ++j)
                    a1[i][j] = fmaf(xa[i], wa[j], a1[i][j]);
        }
#pragma unroll
        for (int j = 0; j < 4; ++j) {
            float b = b1s[c0 + j];
            float4 o;
            o.x = fmaxf(a1[0][j] + b, 0.f);
            o.y = fmaxf(a1[1][j] + b, 0.f);
            o.z = fmaxf(a1[2][j] + b, 0.f);
            o.w = fmaxf(a1[3][j] + b, 0.f);
            *(float4*)&hs[(c0 + j) * 68 + r0] = o;
        }
    }
    __syncthreads();

    // GEMM2: xhat = relu(h @ W2 + b2) -> regs
    float a2[4][4] = {{0.f}};
#pragma unroll 8
    for (int k = 0; k < EMB; ++k) {
        float4 xv = *(const float4*)&hs[k * 68 + r0];
        float4 wv = *(const float4*)&ws[k * EMB + c0];
        float xa[4] = {xv.x, xv.y, xv.z, xv.w};
        float wa[4] = {wv.x, wv.y, wv.z, wv.w};
#pragma unroll
        for (int i = 0; i < 4; ++i)
#pragma unroll
            for (int j = 0; j < 4; ++j)
                a2[i][j] = fmaf(xa[i], wa[j], a2[i][j]);
    }
    __syncthreads();   // all reads of hs (h) and ws (w2) complete

    // store xhat into hs (transposed) ; stage wll into ws
#pragma unroll
    for (int j = 0; j < 4; ++j) {
        float b = b2s[c0 + j];
        float4 o;
        o.x = fmaxf(a2[0][j] + b, 0.f);
        o.y = fmaxf(a2[1][j] + b, 0.f);
        o.z = fmaxf(a2[2][j] + b, 0.f);
        o.w = fmaxf(a2[3][j] + b, 0.f);
        *(float4*)&hs[(c0 + j) * 68 + r0] = o;
    }
    {
        const float4* wg = (const float4*)wll;
        float4* wl = (float4*)ws;
#pragma unroll
        for (int q = 0; q < 4; ++q) wl[t + q * 256] = wg[t + q * 256];
    }
    __syncthreads();

    // GEMM3: t = xhat @ Wll -> bf16 table
    {
        float a3[4][4] = {{0.f}};
#pragma unroll 8
        for (int k = 0; k < EMB; ++k) {
            float4 xv = *(const float4*)&hs[k * 68 + r0];
            float4 wv = *(const float4*)&ws[k * EMB + c0];
            float xa[4] = {xv.x, xv.y, xv.z, xv.w};
            float wa[4] = {wv.x, wv.y, wv.z, wv.w};
#pragma unroll
            for (int i = 0; i < 4; ++i)
#pragma unroll
                for (int j = 0; j < 4; ++j)
                    a3[i][j] = fmaf(xa[i], wa[j], a3[i][j]);
        }
#pragma unroll
        for (int i = 0; i < 4; ++i) {
            long gr = row0 + r0 + i;
            if (gr < n) {
                ushort4 o;
                o.x = f2bf(a3[i][0]); o.y = f2bf(a3[i][1]);
                o.z = f2bf(a3[i][2]); o.w = f2bf(a3[i][3]);
                *(ushort4*)(tb + gr * EMB + c0) = o;
            }
        }
    }
    __syncthreads();   // all reads of ws (wll) complete

    {
        const float4* wg = (const float4*)wlr;
        float4* wl = (float4*)ws;
#pragma unroll
        for (int q = 0; q < 4; ++q) wl[t + q * 256] = wg[t + q * 256];
    }
    __syncthreads();

    // GEMM4: u = xhat @ Wlr -> f32
    {
        float a4[4][4] = {{0.f}};
#pragma unroll 8
        for (int k = 0; k < EMB; ++k) {
            float4 xv = *(const float4*)&hs[k * 68 + r0];
            float4 wv = *(const float4*)&ws[k * EMB + c0];
            float xa[4] = {xv.x, xv.y, xv.z, xv.w};
            float wa[4] = {wv.x, wv.y, wv.z, wv.w};
#pragma unroll
            for (int i = 0; i < 4; ++i)
#pragma unroll
                for (int j = 0; j < 4; ++j)
                    a4[i][j] = fmaf(xa[i], wa[j], a4[i][j]);
        }
#pragma unroll
        for (int i = 0; i < 4; ++i) {
            long gr = row0 + r0 + i;
            if (gr < n)
                *(float4*)&u[gr * EMB + c0] = make_float4(a4[i][0], a4[i][1], a4[i][2], a4[i][3]);
        }
    }
}

// Fused layer-0 agg + layer-1 GEMM. 512 threads = 8 waves, 64 nodes/block
// (degree-sorted via perm -> uniform work per block). xt [r][f] stride-65.
template <bool BF_OUT>
__global__ __launch_bounds__(512) void agg64_kernel(
    const unsigned short* __restrict__ tbl, const int* __restrict__ rowptr,
    const int* __restrict__ adj, const int* __restrict__ perm,
    const float* __restrict__ bias, const float* __restrict__ u,
    const float* __restrict__ W, void* __restrict__ outv, int n)
{
    __shared__ float xt[64 * ST];    // [r][f]
    __shared__ float ws[EMB * EMB];
    __shared__ float bs[EMB];
    __shared__ int nds[64];

    int t = threadIdx.x;
    long node0 = (long)blockIdx.x * 64;
    int lane = t & 63;
    int wv = t >> 6;                 // wave 0..7
    int p = lane & 15, g = lane >> 4;
    int f = 4 * p + g;

    {
        const float4* wg = (const float4*)W;
        float4* wl = (float4*)ws;
        wl[t] = wg[t];
        wl[t + 512] = wg[t + 512];
    }
    if (t < EMB) bs[t] = bias[t];
    if (t < 64) nds[t] = (node0 + t < n) ? perm[node0 + t] : -1;
    __syncthreads();

    const uint2* tb = (const uint2*)tbl;
    float bf = bs[f];
#pragma unroll
    for (int i = 0; i < 8; ++i) {
        int r = wv * 8 + i;
        int node = nds[r];
        float val = 0.f;
        if (node >= 0) {
            int beg = rowptr[node];
            int end = rowptr[node + 1];
            float a0 = 0.f, a1 = 0.f, a2 = 0.f, a3 = 0.f;
            int e = beg + g;
            for (; e + 4 < end; e += 8) {
                int r0 = adj[e];
                int r1 = adj[e + 4];
                uint2 w0 = tb[(long)r0 * 16 + p];
                uint2 w1 = tb[(long)r1 * 16 + p];
                a0 += bflo(w0.x) + bflo(w1.x);
                a1 += bfhi(w0.x) + bfhi(w1.x);
                a2 += bflo(w0.y) + bflo(w1.y);
                a3 += bfhi(w0.y) + bfhi(w1.y);
            }
            if (e < end) {
                uint2 w0 = tb[(long)adj[e] * 16 + p];
                a0 += bflo(w0.x);
                a1 += bfhi(w0.x);
                a2 += bflo(w0.y);
                a3 += bfhi(w0.y);
            }
            a0 += __shfl_xor(a0, 16); a0 += __shfl_xor(a0, 32);
            a1 += __shfl_xor(a1, 16); a1 += __shfl_xor(a1, 32);
            a2 += __shfl_xor(a2, 16); a2 += __shfl_xor(a2, 32);
            a3 += __shfl_xor(a3, 16); a3 += __shfl_xor(a3, 32);
            int cnt = end - beg;
            float inv = 1.f / (float)(cnt > 0 ? cnt : 1);
            float av = (g == 0) ? a0 : ((g == 1) ? a1 : ((g == 2) ? a2 : a3));
            val = fmaxf(av * inv + bf + u[(long)node * EMB + f], 0.f);
        }
        xt[r * ST + f] = val;
    }
    __syncthreads();

    // GEMM: 2 rows x 4 cols per thread; xt reads scalar (broadcast), ws float4
    int c0 = (t & 15) * 4;
    int r0 = (t >> 4) * 2;
    float acc[2][4] = {{0.f}};
#pragma unroll 8
    for (int k = 0; k < EMB; ++k) {
        float xa0 = xt[r0 * ST + k];
        float xa1 = xt[(r0 + 1) * ST + k];
        float4 wv4 = *(const float4*)&ws[k * EMB + c0];
        acc[0][0] = fmaf(xa0, wv4.x, acc[0][0]);
        acc[0][1] = fmaf(xa0, wv4.y, acc[0][1]);
        acc[0][2] = fmaf(xa0, wv4.z, acc[0][2]);
        acc[0][3] = fmaf(xa0, wv4.w, acc[0][3]);
        acc[1][0] = fmaf(xa1, wv4.x, acc[1][0]);
        acc[1][1] = fmaf(xa1, wv4.y, acc[1][1]);
        acc[1][2] = fmaf(xa1, wv4.z, acc[1][2]);
        acc[1][3] = fmaf(xa1, wv4.w, acc[1][3]);
    }
#pragma unroll
    for (int i = 0; i < 2; ++i) {
        int node = nds[r0 + i];
        if (node >= 0) {
            if (BF_OUT) {
                ushort4 o;
                o.x = f2bf(acc[i][0]); o.y = f2bf(acc[i][1]);
                o.z = f2bf(acc[i][2]); o.w = f2bf(acc[i][3]);
                *(ushort4*)((unsigned short*)outv + (long)node * EMB + c0) = o;
            } else {
                *(float4*)((float*)outv + (long)node * EMB + c0) =
                    make_float4(acc[i][0], acc[i][1], acc[i][2], acc[i][3]);
            }
        }
    }
}

// Final layer: out[node] = relu(mean_nbr tb[nbr] + bias + out[node])  (RMW)
__global__ __launch_bounds__(256) void agg_bf16_kernel(
    const unsigned short* __restrict__ tbl, const int* __restrict__ rowptr,
    const int* __restrict__ adj, const int* __restrict__ perm,
    const float* __restrict__ bias, float* __restrict__ out, int n_dst)
{
    int lane = threadIdx.x & 63;
    int idx = blockIdx.x * 4 + (threadIdx.x >> 6);
    if (idx >= n_dst) return;
    int node = perm[idx];
    int p = lane & 15;
    int g = lane >> 4;
    int beg = rowptr[node];
    int end = rowptr[node + 1];
    const uint2* tb = (const uint2*)tbl;
    float a0 = 0.f, a1 = 0.f, a2 = 0.f, a3 = 0.f;
    int e = beg + g;
    for (; e + 4 < end; e += 8) {
        int r0 = adj[e];
        int r1 = adj[e + 4];
        uint2 w0 = tb[(long)r0 * 16 + p];
        uint2 w1 = tb[(long)r1 * 16 + p];
        a0 += bflo(w0.x) + bflo(w1.x);
        a1 += bfhi(w0.x) + bfhi(w1.x);
        a2 += bflo(w0.y) + bflo(w1.y);
        a3 += bfhi(w0.y) + bfhi(w1.y);
    }
    if (e < end) {
        uint2 w0 = tb[(long)adj[e] * 16 + p];
        a0 += bflo(w0.x);
        a1 += bfhi(w0.x);
        a2 += bflo(w0.y);
        a3 += bfhi(w0.y);
    }
    a0 += __shfl_xor(a0, 16); a0 += __shfl_xor(a0, 32);
    a1 += __shfl_xor(a1, 16); a1 += __shfl_xor(a1, 32);
    a2 += __shfl_xor(a2, 16); a2 += __shfl_xor(a2, 32);
    a3 += __shfl_xor(a3, 16); a3 += __shfl_xor(a3, 32);
    if (g == 0) {
        int cnt = end - beg;
        float inv = 1.f / (float)(cnt > 0 ? cnt : 1);
        float4 bv = ((const float4*)bias)[p];
        float4* op = (float4*)(out + (long)node * EMB) + p;
        float4 ov = *op;
        float v0 = a0 * inv + bv.x + ov.x;
        float v1 = a1 * inv + bv.y + ov.y;
        float v2 = a2 * inv + bv.z + ov.z;
        float v3 = a3 * inv + bv.w + ov.w;
        *op = make_float4(fmaxf(v0, 0.f), fmaxf(v1, 0.f), fmaxf(v2, 0.f), fmaxf(v3, 0.f));
    }
}

extern "C" void kernel_launch(void* const* d_in, const int* in_sizes, int n_in,
                              void* d_out, int out_size, void* d_ws, size_t ws_size,
                              hipStream_t stream) {
    const float* cons_x     = (const float*)d_in[0];
    const float* var_x      = (const float*)d_in[1];
    const int*   eidx       = (const int*)d_in[3];
    const float* cons_shift = (const float*)d_in[4];
    const float* cons_scale = (const float*)d_in[5];
    const float* cons_w1    = (const float*)d_in[6];
    const float* cons_b1    = (const float*)d_in[7];
    const float* cons_w2    = (const float*)d_in[8];
    const float* cons_b2    = (const float*)d_in[9];
    const float* var_shift  = (const float*)d_in[10];
    const float* var_scale  = (const float*)d_in[11];
    const float* var_w1     = (const float*)d_in[12];
    const float* var_b1     = (const float*)d_in[13];
    const float* var_w2     = (const float*)d_in[14];
    const float* var_b2     = (const float*)d_in[15];
    const float* ll_w       = (const float*)d_in[18];
    const float* ll_b       = (const float*)d_in[19];
    const float* lr_w       = (const float*)d_in[20];

    const int nC = in_sizes[0] / 5;
    const int nV = in_sizes[1] / 19;
    const int E  = in_sizes[3] / 2;
    const int* src = eidx;       // constraint ids
    const int* dst = eidx + E;   // variable ids

    int shc = 0; while ((nC >> shc) >= 512) ++shc;
    int shv = 0; while ((nV >> shv) >= 512) ++shv;
    const int NBC = (nC + (1 << shc) - 1) >> shc;
    const int NBV = (nV + (1 << shv) - 1) >> shv;

    char* w = (char*)d_ws;
    auto alloc = [&](size_t bytes) {
        char* p = w;
        w += (bytes + 255) & ~(size_t)255;
        return p;
    };
    float* x_c = (float*)alloc((size_t)nC * EMB * 4);   // u_c buffer
    float* x_v = (float*)alloc((size_t)nV * EMB * 4);   // u_v buffer
    float* t_c = (float*)alloc((size_t)nC * EMB * 4);   // aliases: tmp_c, then bf16 table tb_c
    float* t_v = (float*)alloc((size_t)nV * EMB * 4);
    unsigned* tmp_c = (unsigned*)t_c;
    unsigned* tmp_v = (unsigned*)t_v;
    unsigned short* tb_c = (unsigned short*)t_c;
    unsigned short* tb_v = (unsigned short*)t_v;
    int* rp_v  = (int*)alloc((size_t)(nV + 1) * 4);
    int* rp_c  = (int*)alloc((size_t)(nC + 1) * 4);
    int* adj_v = (int*)alloc((size_t)E * 4);
    int* adj_c = (int*)alloc((size_t)E * 4);
    int* perm_v = (int*)alloc((size_t)nV * 4);
    int* perm_c = (int*)alloc((size_t)nC * 4);
    int* bkt   = (int*)alloc(4096 * 4);
    int* bb_c   = bkt;
    int* bb_v   = bkt + 1024;
    int* gcur_c = bkt + 2048;
    int* gcur_v = bkt + 3072;
    int* dsort  = (int*)alloc(4096 * 4);
    int* bins_c = dsort;          // 513
    int* bins_v = dsort + 1024;   // 513
    int* dcur_c = dsort + 2048;   // 512
    int* dcur_v = dsort + 3072;   // 512

    auto llw = [&](int l, int d) { return ll_w + (size_t)(l * 2 + d) * EMB * EMB; };
    auto lrw = [&](int l, int d) { return lr_w + (size_t)(l * 2 + d) * EMB * EMB; };
    auto llb = [&](int l, int d) { return ll_b + (size_t)(l * 2 + d) * EMB; };

    // ---- CSR build ----
    zero_int_kernel<<<32, 256, 0, stream>>>(bkt, 8192);   // bkt + dsort (contiguous allocs)
    bucket_hist_kernel<<<(E + CH - 1) / CH, 256, 0, stream>>>(src, dst, E, bb_c, bb_v, shc, shv, NBC, NBV);
    scan_buckets_kernel<<<1, 256, 0, stream>>>(bb_c, NBC, bb_v, NBV, E);
    bin_edges_kernel<<<(E + CH - 1) / CH, 256, 0, stream>>>(src, dst, E, bb_c, bb_v, gcur_c, gcur_v,
                                                            tmp_c, tmp_v, shc, shv, NBC, NBV);
    regroup2_kernel<<<NBV, 256, 0, stream>>>(tmp_v, bb_v, rp_v, adj_v, nV, shv, E, NBV);
    regroup2_kernel<<<NBC, 256, 0, stream>>>(tmp_c, bb_c, rp_c, adj_c, nC, shc, E, NBC);

    // ---- degree-sort permutations (uniform work per agg block) ----
    deg_hist_kernel<<<(nV + 2047) / 2048, 256, 0, stream>>>(rp_v, nV, bins_v);
    deg_hist_kernel<<<(nC + 2047) / 2048, 256, 0, stream>>>(rp_c, nC, bins_c);
    scan_buckets_kernel<<<1, 256, 0, stream>>>(bins_c, 512, bins_v, 512, 0);
    deg_scatter_kernel<<<(nV + 2047) / 2048, 256, 0, stream>>>(rp_v, nV, bins_v, dcur_v, perm_v);
    deg_scatter_kernel<<<(nC + 2047) / 2048, 256, 0, stream>>>(rp_c, nC, bins_c, dcur_c, perm_c);

    // ---- fused embed + layer-0 GEMMs (x never hits HBM) ----
    embed_fused_kernel<5><<<(nC + 63) / 64, 256, 0, stream>>>(
        cons_x, cons_shift, cons_scale, cons_w1, cons_b1, cons_w2, cons_b2,
        llw(0, 0), lrw(0, 1), tb_c, x_c, nC);
    embed_fused_kernel<19><<<(nV + 63) / 64, 256, 0, stream>>>(
        var_x, var_shift, var_scale, var_w1, var_b1, var_w2, var_b2,
        llw(0, 1), lrw(0, 0), tb_v, x_v, nV);

    // ---- layer-0 agg fused with layer-1 GEMM (degree-balanced blocks) ----
    agg64_kernel<false><<<(nV + 63) / 64, 512, 0, stream>>>(
        tb_c, rp_v, adj_v, perm_v, llb(0, 0), x_v, lrw(1, 0), d_out, nV);
    agg64_kernel<true><<<(nC + 63) / 64, 512, 0, stream>>>(
        tb_v, rp_c, adj_c, perm_c, llb(0, 1), x_c, llw(1, 0), tb_c, nC);

    // ---- final layer-1 var agg (RMW d_out) ----
    agg_bf16_kernel<<<(nV + 3) / 4, 256, 0, stream>>>(tb_c, rp_v, adj_v, perm_v, llb(1, 0), (float*)d_out, nV);
}

// Round 10
// 488.773 us; speedup vs baseline: 1.0543x; 1.0543x over previous
//
#include <hip/hip_runtime.h>

#define EMB 64
#define CH 4096

// ---------------------------------------------------------------------------
// Round 10: de-fuse the aggregation (r7-r9 showed agg(+)GEMM fusion costs
// ~30us in the gather to save ~16us of GEMM: any 64-node block+barrier
// structure pays max-over-degree or locality tax; the standalone 50k-block
// agg gets dynamic load balance free).
//  - agg_rmw: r6's proven standalone form (4 nodes/block, 1 node/wave,
//    4-slot 8B gather, no barrier). 79us var / 40us cons.
//  - layer-1 GEMMs: thin gemm64 dispatches (bf16 out for tb_c, f32 for d_out).
//  - embed_fused kept from r7 (real win: prenorm+MLP+both layer-0 GEMMs,
//    x and xhat never round-trip HBM).
//  - no perm / degree sort (r9: +15MB fetch, net loss).
// ---------------------------------------------------------------------------

static __device__ __forceinline__ unsigned short f2bf(float x) {
    union { float f; unsigned u; } v; v.f = x;
    unsigned r = v.u + 0x7fffu + ((v.u >> 16) & 1u);   // RNE
    return (unsigned short)(r >> 16);
}
static __device__ __forceinline__ float bflo(unsigned w) {
    union { unsigned u; float f; } v; v.u = w << 16; return v.f;
}
static __device__ __forceinline__ float bfhi(unsigned w) {
    union { unsigned u; float f; } v; v.u = w & 0xffff0000u; return v.f;
}

__global__ __launch_bounds__(256) void zero_int_kernel(int* __restrict__ p, int n) {
    int i = blockIdx.x * 256 + threadIdx.x;
    if (i < n) p[i] = 0;
}

__global__ __launch_bounds__(256) void bucket_hist_kernel(
    const int* __restrict__ src, const int* __restrict__ dst, int E,
    int* __restrict__ bkt_cnt_c, int* __restrict__ bkt_cnt_v,
    int shc, int shv, int NBC, int NBV)
{
    __shared__ int hc[512], hv[512];
    int t = threadIdx.x;
    int base = blockIdx.x * CH;
    int n = min(CH, E - base);
    for (int i = t; i < NBC; i += 256) hc[i] = 0;
    for (int i = t; i < NBV; i += 256) hv[i] = 0;
    __syncthreads();
    for (int li = t; li < n; li += 256) {
        atomicAdd(&hc[src[base + li] >> shc], 1);
        atomicAdd(&hv[dst[base + li] >> shv], 1);
    }
    __syncthreads();
    for (int i = t; i < NBC; i += 256) { int c = hc[i]; if (c) atomicAdd(&bkt_cnt_c[i], c); }
    for (int i = t; i < NBV; i += 256) { int c = hv[i]; if (c) atomicAdd(&bkt_cnt_v[i], c); }
}

// one block: exclusive-scan both bucket-count arrays in place; data[n] = E
__global__ __launch_bounds__(256) void scan_buckets_kernel(
    int* __restrict__ bc, int nbc, int* __restrict__ bv, int nbv, int E)
{
    __shared__ int sc[256];
    int t = threadIdx.x;
    {
        int v0 = (2 * t < nbc) ? bc[2 * t] : 0;
        int v1 = (2 * t + 1 < nbc) ? bc[2 * t + 1] : 0;
        sc[t] = v0 + v1;
        __syncthreads();
        for (int off = 1; off < 256; off <<= 1) {
            int x = (t >= off) ? sc[t - off] : 0;
            __syncthreads();
            sc[t] += x;
            __syncthreads();
        }
        int ex = (t > 0) ? sc[t - 1] : 0;
        if (2 * t < nbc) bc[2 * t] = ex;
        if (2 * t + 1 < nbc) bc[2 * t + 1] = ex + v0;
        if (t == 0) bc[nbc] = E;
        __syncthreads();
    }
    {
        int v0 = (2 * t < nbv) ? bv[2 * t] : 0;
        int v1 = (2 * t + 1 < nbv) ? bv[2 * t + 1] : 0;
        sc[t] = v0 + v1;
        __syncthreads();
        for (int off = 1; off < 256; off <<= 1) {
            int x = (t >= off) ? sc[t - off] : 0;
            __syncthreads();
            sc[t] += x;
            __syncthreads();
        }
        int ex = (t > 0) ? sc[t - 1] : 0;
        if (2 * t < nbv) bv[2 * t] = ex;
        if (2 * t + 1 < nbv) bv[2 * t + 1] = ex + v0;
        if (t == 0) bv[nbv] = E;
    }
}

// Phase 1: per-chunk LDS binning; packed u32 {local_node<<23 | other}.
__global__ __launch_bounds__(256) void bin_edges_kernel(
    const int* __restrict__ src, const int* __restrict__ dst, int E,
    const int* __restrict__ bb_c, const int* __restrict__ bb_v,
    int* __restrict__ gcur_c, int* __restrict__ gcur_v,
    unsigned* __restrict__ tmp_c, unsigned* __restrict__ tmp_v,
    int shc, int shv, int NBC, int NBV)
{
    __shared__ int hc[512], hv[512];
    int t = threadIdx.x;
    int base = blockIdx.x * CH;
    int n = min(CH, E - base);
    unsigned mc = (1u << shc) - 1u, mv = (1u << shv) - 1u;

    for (int i = t; i < NBC; i += 256) hc[i] = 0;
    for (int i = t; i < NBV; i += 256) hv[i] = 0;
    __syncthreads();

    int ss[16], dd[16];
#pragma unroll
    for (int q = 0; q < 16; ++q) {
        int li = t + q * 256;
        bool ok = li < n;
        ss[q] = ok ? src[base + li] : -1;
        dd[q] = ok ? dst[base + li] : -1;
        if (ok) {
            atomicAdd(&hc[ss[q] >> shc], 1);
            atomicAdd(&hv[dd[q] >> shv], 1);
        }
    }
    __syncthreads();

    for (int i = t; i < NBC; i += 256) {
        int c = hc[i];
        hc[i] = c ? (bb_c[i] + atomicAdd(&gcur_c[i], c)) : 0;
    }
    for (int i = t; i < NBV; i += 256) {
        int c = hv[i];
        hv[i] = c ? (bb_v[i] + atomicAdd(&gcur_v[i], c)) : 0;
    }
    __syncthreads();

#pragma unroll
    for (int q = 0; q < 16; ++q) {
        int li = t + q * 256;
        if (li < n) {
            unsigned s = (unsigned)ss[q], d = (unsigned)dd[q];
            int pc = atomicAdd(&hc[s >> shc], 1);
            tmp_c[pc] = ((s & mc) << 23) | d;
            int pv = atomicAdd(&hv[d >> shv], 1);
            tmp_v[pv] = ((d & mv) << 23) | s;
        }
    }
}

// Phase 2: wg-per-bucket. LDS per-node hist -> scan -> rp; rank -> adj.
__global__ __launch_bounds__(256) void regroup2_kernel(
    const unsigned* __restrict__ tmp, const int* __restrict__ bb,
    int* __restrict__ rp, int* __restrict__ adj, int n_nodes, int sh, int E, int nb)
{
    __shared__ int cnt[512];
    __shared__ int offs[512];
    __shared__ int sc[256];
    int t = threadIdx.x;
    int b = blockIdx.x;
    int node0 = b << sh;
    int node1 = min(node0 + (1 << sh), n_nodes);
    int nn = node1 - node0;
    for (int i = t; i < nn; i += 256) cnt[i] = 0;
    __syncthreads();
    int beg = bb[b], end = bb[b + 1];
    for (int e = beg + t; e < end; e += 256)
        atomicAdd(&cnt[tmp[e] >> 23], 1);
    __syncthreads();
    int v0 = (2 * t < nn) ? cnt[2 * t] : 0;
    int v1 = (2 * t + 1 < nn) ? cnt[2 * t + 1] : 0;
    sc[t] = v0 + v1;
    __syncthreads();
    for (int off = 1; off < 256; off <<= 1) {
        int x = (t >= off) ? sc[t - off] : 0;
        __syncthreads();
        sc[t] += x;
        __syncthreads();
    }
    int ex = (t > 0) ? sc[t - 1] : 0;
    if (2 * t < nn) offs[2 * t] = ex;
    if (2 * t + 1 < nn) offs[2 * t + 1] = ex + v0;
    __syncthreads();
    for (int i = t; i < nn; i += 256) {
        rp[node0 + i] = beg + offs[i];
        cnt[i] = 0;
    }
    if (b == nb - 1 && t == 0) rp[n_nodes] = E;
    __syncthreads();
    for (int e = beg + t; e < end; e += 256) {
        unsigned p = tmp[e];
        int d = (int)(p >> 23);
        int r = atomicAdd(&cnt[d], 1);
        adj[beg + offs[d] + r] = (int)(p & 0x7fffffu);
    }
}

// Fully fused node pipeline:
//   xhat = relu(relu(((x+shift)*scale)@W1+b1)@W2+b2)   (LDS only)
//   tb   = bf16(xhat @ Wll)      (layer-0 gather table)
//   u    = xhat @ Wlr            (layer-0 self term, f32)
template <int NF>
__global__ __launch_bounds__(256) void embed_fused_kernel(
    const float* __restrict__ x, const float* __restrict__ shift, const float* __restrict__ scale,
    const float* __restrict__ w1, const float* __restrict__ b1,
    const float* __restrict__ w2, const float* __restrict__ b2,
    const float* __restrict__ wll, const float* __restrict__ wlr,
    unsigned short* __restrict__ tb, float* __restrict__ u, int n)
{
    __shared__ float xs[NF * 68];
    __shared__ float w1s[NF * EMB];
    __shared__ float hs[EMB * 68];    // h, then xhat (transposed [k][r])
    __shared__ float ws[EMB * EMB];   // w2 -> wll -> wlr
    __shared__ float b1s[EMB], b2s[EMB];

    int t = threadIdx.x;
    long row0 = (long)blockIdx.x * 64;
    int nrow = (int)((n - row0 < 64) ? (n - row0) : 64);

    for (int i = t; i < NF * EMB; i += 256) w1s[i] = w1[i];
    if (t < EMB) { b1s[t] = b1[t]; b2s[t] = b2[t]; }
    {
        const float4* wg = (const float4*)w2;
        float4* wl = (float4*)ws;
#pragma unroll
        for (int q = 0; q < 4; ++q) wl[t + q * 256] = wg[t + q * 256];
    }
    for (int i = t; i < 64 * NF; i += 256) {
        int r = i / NF, k = i - r * NF;
        float v = (r < nrow) ? x[row0 * NF + i] : 0.f;
        xs[k * 68 + r] = (v + shift[k]) * scale[k];
    }
    __syncthreads();

    int r0 = (t >> 4) * 4;
    int c0 = (t & 15) * 4;

    // GEMM1: h = relu(xs @ W1 + b1), stored transposed into hs
    {
        float a1[4][4] = {{0.f}};
#pragma unroll
        for (int k = 0; k < NF; ++k) {
            float4 xv = *(const float4*)&xs[k * 68 + r0];
            float4 wv = *(const float4*)&w1s[k * EMB + c0];
            float xa[4] = {xv.x, xv.y, xv.z, xv.w};
            float wa[4] = {wv.x, wv.y, wv.z, wv.w};
#pragma unroll
            for (int i = 0; i < 4; ++i)
#pragma unroll
                for (int j = 0; j < 4; ++j)
                    a1[i][j] = fmaf(xa[i], wa[j], a1[i][j]);
        }
#pragma unroll
        for (int j = 0; j < 4; ++j) {
            float b = b1s[c0 + j];
            float4 o;
            o.x = fmaxf(a1[0][j] + b, 0.f);
            o.y = fmaxf(a1[1][j] + b, 0.f);
            o.z = fmaxf(a1[2][j] + b, 0.f);
            o.w = fmaxf(a1[3][j] + b, 0.f);
            *(float4*)&hs[(c0 + j) * 68 + r0] = o;
        }
    }
    __syncthreads();

    // GEMM2: xhat = relu(h @ W2 + b2) -> regs
    float a2[4][4] = {{0.f}};
#pragma unroll 8
    for (int k = 0; k < EMB; ++k) {
        float4 xv = *(const float4*)&hs[k * 68 + r0];
        float4 wv = *(const float4*)&ws[k * EMB + c0];
        float xa[4] = {xv.x, xv.y, xv.z, xv.w};
        float wa[4] = {wv.x, wv.y, wv.z, wv.w};
#pragma unroll
        for (int i = 0; i < 4; ++i)
#pragma unroll
            for (int j = 0; j < 4; ++j)
                a2[i][j] = fmaf(xa[i], wa[j], a2[i][j]);
    }
    __syncthreads();   // all reads of hs (h) and ws (w2) complete

    // store xhat into hs (transposed) ; stage wll into ws
#pragma unroll
    for (int j = 0; j < 4; ++j) {
        float b = b2s[c0 + j];
        float4 o;
        o.x = fmaxf(a2[0][j] + b, 0.f);
        o.y = fmaxf(a2[1][j] + b, 0.f);
        o.z = fmaxf(a2[2][j] + b, 0.f);
        o.w = fmaxf(a2[3][j] + b, 0.f);
        *(float4*)&hs[(c0 + j) * 68 + r0] = o;
    }
    {
        const float4* wg = (const float4*)wll;
        float4* wl = (float4*)ws;
#pragma unroll
        for (int q = 0; q < 4; ++q) wl[t + q * 256] = wg[t + q * 256];
    }
    __syncthreads();

    // GEMM3: t = xhat @ Wll -> bf16 table
    {
        float a3[4][4] = {{0.f}};
#pragma unroll 8
        for (int k = 0; k < EMB; ++k) {
            float4 xv = *(const float4*)&hs[k * 68 + r0];
            float4 wv = *(const float4*)&ws[k * EMB + c0];
            float xa[4] = {xv.x, xv.y, xv.z, xv.w};
            float wa[4] = {wv.x, wv.y, wv.z, wv.w};
#pragma unroll
            for (int i = 0; i < 4; ++i)
#pragma unroll
                for (int j = 0; j < 4; ++j)
                    a3[i][j] = fmaf(xa[i], wa[j], a3[i][j]);
        }
#pragma unroll
        for (int i = 0; i < 4; ++i) {
            long gr = row0 + r0 + i;
            if (gr < n) {
                ushort4 o;
                o.x = f2bf(a3[i][0]); o.y = f2bf(a3[i][1]);
                o.z = f2bf(a3[i][2]); o.w = f2bf(a3[i][3]);
                *(ushort4*)(tb + gr * EMB + c0) = o;
            }
        }
    }
    __syncthreads();   // all reads of ws (wll) complete

    {
        const float4* wg = (const float4*)wlr;
        float4* wl = (float4*)ws;
#pragma unroll
        for (int q = 0; q < 4; ++q) wl[t + q * 256] = wg[t + q * 256];
    }
    __syncthreads();

    // GEMM4: u = xhat @ Wlr -> f32
    {
        float a4[4][4] = {{0.f}};
#pragma unroll 8
        for (int k = 0; k < EMB; ++k) {
            float4 xv = *(const float4*)&hs[k * 68 + r0];
            float4 wv = *(const float4*)&ws[k * EMB + c0];
            float xa[4] = {xv.x, xv.y, xv.z, xv.w};
            float wa[4] = {wv.x, wv.y, wv.z, wv.w};
#pragma unroll
            for (int i = 0; i < 4; ++i)
#pragma unroll
                for (int j = 0; j < 4; ++j)
                    a4[i][j] = fmaf(xa[i], wa[j], a4[i][j]);
        }
#pragma unroll
        for (int i = 0; i < 4; ++i) {
            long gr = row0 + r0 + i;
            if (gr < n)
                *(float4*)&u[gr * EMB + c0] = make_float4(a4[i][0], a4[i][1], a4[i][2], a4[i][3]);
        }
    }
}

// C = act(X@W), bf16 or f32 out. 64-row tile; X staged transposed in LDS.
template <bool BF1>
__global__ __launch_bounds__(256) void gemm64_kernel(
    const float* __restrict__ X, int n,
    const float* __restrict__ W, void* __restrict__ Cv)
{
    __shared__ float xs[EMB * 68];            // transposed tile: xs[k*68 + r]
    __shared__ float w1s[EMB * EMB];

    int t = threadIdx.x;
    {
        int r = t >> 2;
        int cs = (t & 3) * 16;
        long gr = (long)blockIdx.x * 64 + r;
        float4 v[4];
        if (gr < n) {
            const float4* sp = (const float4*)(X + gr * EMB + cs);
#pragma unroll
            for (int q = 0; q < 4; ++q) v[q] = sp[q];
        } else {
            float4 z = make_float4(0.f, 0.f, 0.f, 0.f);
#pragma unroll
            for (int q = 0; q < 4; ++q) v[q] = z;
        }
#pragma unroll
        for (int q = 0; q < 4; ++q) {
            xs[(cs + q * 4 + 0) * 68 + r] = v[q].x;
            xs[(cs + q * 4 + 1) * 68 + r] = v[q].y;
            xs[(cs + q * 4 + 2) * 68 + r] = v[q].z;
            xs[(cs + q * 4 + 3) * 68 + r] = v[q].w;
        }
        const float4* wg = (const float4*)W;
        float4* wl = (float4*)w1s;
#pragma unroll
        for (int q = 0; q < 4; ++q) wl[t + q * 256] = wg[t + q * 256];
    }
    __syncthreads();

    int r0 = (t >> 4) * 4;
    int c0 = (t & 15) * 4;
    float acc[4][4] = {{0.f}};
#pragma unroll 8
    for (int k = 0; k < EMB; ++k) {
        float4 xv = *(const float4*)&xs[k * 68 + r0];
        float4 wv = *(const float4*)&w1s[k * EMB + c0];
        float xa[4] = {xv.x, xv.y, xv.z, xv.w};
        float wa[4] = {wv.x, wv.y, wv.z, wv.w};
#pragma unroll
        for (int i = 0; i < 4; ++i)
#pragma unroll
            for (int j = 0; j < 4; ++j)
                acc[i][j] = fmaf(xa[i], wa[j], acc[i][j]);
    }

#pragma unroll
    for (int i = 0; i < 4; ++i) {
        long gr = (long)blockIdx.x * 64 + r0 + i;
        if (gr < n) {
            if (BF1) {
                ushort4 o;
                o.x = f2bf(acc[i][0]); o.y = f2bf(acc[i][1]);
                o.z = f2bf(acc[i][2]); o.w = f2bf(acc[i][3]);
                *(ushort4*)((unsigned short*)Cv + gr * EMB + c0) = o;
            } else {
                *(float4*)((float*)Cv + gr * EMB + c0) =
                    make_float4(acc[i][0], acc[i][1], acc[i][2], acc[i][3]);
            }
        }
    }
}

// out[node] = relu(mean_nbr tb[nbr] + bias + out[node])  (RMW; out holds u)
// 4 nodes/block, 1 node/wave. lane = 16*g + p: slot g in {0..3}, 8B/lane.
__global__ __launch_bounds__(256) void agg_rmw_kernel(
    const unsigned short* __restrict__ tbl, const int* __restrict__ rowptr,
    const int* __restrict__ adj, const float* __restrict__ bias,
    float* __restrict__ out, int n_dst)
{
    int lane = threadIdx.x & 63;
    int node = blockIdx.x * 4 + (threadIdx.x >> 6);
    if (node >= n_dst) return;
    int p = lane & 15;
    int g = lane >> 4;
    int beg = rowptr[node];
    int end = rowptr[node + 1];
    const uint2* tb = (const uint2*)tbl;
    float a0 = 0.f, a1 = 0.f, a2 = 0.f, a3 = 0.f;
    int e = beg + g;
    for (; e + 4 < end; e += 8) {
        int r0 = adj[e];
        int r1 = adj[e + 4];
        uint2 w0 = tb[(long)r0 * 16 + p];
        uint2 w1 = tb[(long)r1 * 16 + p];
        a0 += bflo(w0.x) + bflo(w1.x);
        a1 += bfhi(w0.x) + bfhi(w1.x);
        a2 += bflo(w0.y) + bflo(w1.y);
        a3 += bfhi(w0.y) + bfhi(w1.y);
    }
    if (e < end) {
        uint2 w0 = tb[(long)adj[e] * 16 + p];
        a0 += bflo(w0.x);
        a1 += bfhi(w0.x);
        a2 += bflo(w0.y);
        a3 += bfhi(w0.y);
    }
    a0 += __shfl_xor(a0, 16); a0 += __shfl_xor(a0, 32);
    a1 += __shfl_xor(a1, 16); a1 += __shfl_xor(a1, 32);
    a2 += __shfl_xor(a2, 16); a2 += __shfl_xor(a2, 32);
    a3 += __shfl_xor(a3, 16); a3 += __shfl_xor(a3, 32);
    if (g == 0) {
        int cnt = end - beg;
        float inv = 1.f / (float)(cnt > 0 ? cnt : 1);
        float4 bv = ((const float4*)bias)[p];
        float4* op = (float4*)(out + (long)node * EMB) + p;
        float4 ov = *op;
        float v0 = a0 * inv + bv.x + ov.x;
        float v1 = a1 * inv + bv.y + ov.y;
        float v2 = a2 * inv + bv.z + ov.z;
        float v3 = a3 * inv + bv.w + ov.w;
        *op = make_float4(fmaxf(v0, 0.f), fmaxf(v1, 0.f), fmaxf(v2, 0.f), fmaxf(v3, 0.f));
    }
}

extern "C" void kernel_launch(void* const* d_in, const int* in_sizes, int n_in,
                              void* d_out, int out_size, void* d_ws, size_t ws_size,
                              hipStream_t stream) {
    const float* cons_x     = (const float*)d_in[0];
    const float* var_x      = (const float*)d_in[1];
    const int*   eidx       = (const int*)d_in[3];
    const float* cons_shift = (const float*)d_in[4];
    const float* cons_scale = (const float*)d_in[5];
    const float* cons_w1    = (const float*)d_in[6];
    const float* cons_b1    = (const float*)d_in[7];
    const float* cons_w2    = (const float*)d_in[8];
    const float* cons_b2    = (const float*)d_in[9];
    const float* var_shift  = (const float*)d_in[10];
    const float* var_scale  = (const float*)d_in[11];
    const float* var_w1     = (const float*)d_in[12];
    const float* var_b1     = (const float*)d_in[13];
    const float* var_w2     = (const float*)d_in[14];
    const float* var_b2     = (const float*)d_in[15];
    const float* ll_w       = (const float*)d_in[18];
    const float* ll_b       = (const float*)d_in[19];
    const float* lr_w       = (const float*)d_in[20];

    const int nC = in_sizes[0] / 5;
    const int nV = in_sizes[1] / 19;
    const int E  = in_sizes[3] / 2;
    const int* src = eidx;       // constraint ids
    const int* dst = eidx + E;   // variable ids

    int shc = 0; while ((nC >> shc) >= 512) ++shc;
    int shv = 0; while ((nV >> shv) >= 512) ++shv;
    const int NBC = (nC + (1 << shc) - 1) >> shc;
    const int NBV = (nV + (1 << shv) - 1) >> shv;

    char* w = (char*)d_ws;
    auto alloc = [&](size_t bytes) {
        char* p = w;
        w += (bytes + 255) & ~(size_t)255;
        return p;
    };
    float* x_c = (float*)alloc((size_t)nC * EMB * 4);   // u_c, then xhat_c
    float* x_v = (float*)alloc((size_t)nV * EMB * 4);   // u_v, then xhat_v
    float* t_c = (float*)alloc((size_t)nC * EMB * 4);   // aliases: tmp_c, then bf16 table tb_c
    float* t_v = (float*)alloc((size_t)nV * EMB * 4);
    unsigned* tmp_c = (unsigned*)t_c;
    unsigned* tmp_v = (unsigned*)t_v;
    unsigned short* tb_c = (unsigned short*)t_c;
    unsigned short* tb_v = (unsigned short*)t_v;
    int* rp_v  = (int*)alloc((size_t)(nV + 1) * 4);
    int* rp_c  = (int*)alloc((size_t)(nC + 1) * 4);
    int* adj_v = (int*)alloc((size_t)E * 4);
    int* adj_c = (int*)alloc((size_t)E * 4);
    int* bkt   = (int*)alloc(4096 * 4);
    int* bb_c   = bkt;
    int* bb_v   = bkt + 1024;
    int* gcur_c = bkt + 2048;
    int* gcur_v = bkt + 3072;

    auto llw = [&](int l, int d) { return ll_w + (size_t)(l * 2 + d) * EMB * EMB; };
    auto lrw = [&](int l, int d) { return lr_w + (size_t)(l * 2 + d) * EMB * EMB; };
    auto llb = [&](int l, int d) { return ll_b + (size_t)(l * 2 + d) * EMB; };

    // ---- CSR build ----
    zero_int_kernel<<<16, 256, 0, stream>>>(bkt, 4096);
    bucket_hist_kernel<<<(E + CH - 1) / CH, 256, 0, stream>>>(src, dst, E, bb_c, bb_v, shc, shv, NBC, NBV);
    scan_buckets_kernel<<<1, 256, 0, stream>>>(bb_c, NBC, bb_v, NBV, E);
    bin_edges_kernel<<<(E + CH - 1) / CH, 256, 0, stream>>>(src, dst, E, bb_c, bb_v, gcur_c, gcur_v,
                                                            tmp_c, tmp_v, shc, shv, NBC, NBV);
    regroup2_kernel<<<NBV, 256, 0, stream>>>(tmp_v, bb_v, rp_v, adj_v, nV, shv, E, NBV);
    regroup2_kernel<<<NBC, 256, 0, stream>>>(tmp_c, bb_c, rp_c, adj_c, nC, shc, E, NBC);

    // ---- fused embed + layer-0 GEMMs (x, xhat never round-trip HBM) ----
    embed_fused_kernel<5><<<(nC + 63) / 64, 256, 0, stream>>>(
        cons_x, cons_shift, cons_scale, cons_w1, cons_b1, cons_w2, cons_b2,
        llw(0, 0), lrw(0, 1), tb_c, x_c, nC);
    embed_fused_kernel<19><<<(nV + 63) / 64, 256, 0, stream>>>(
        var_x, var_shift, var_scale, var_w1, var_b1, var_w2, var_b2,
        llw(0, 1), lrw(0, 0), tb_v, x_v, nV);

    // ---- layer-0 aggs (RMW u -> xhat) ----
    agg_rmw_kernel<<<(nV + 3) / 4, 256, 0, stream>>>(tb_c, rp_v, adj_v, llb(0, 0), x_v, nV);
    agg_rmw_kernel<<<(nC + 3) / 4, 256, 0, stream>>>(tb_v, rp_c, adj_c, llb(0, 1), x_c, nC);

    // ---- layer-1 GEMMs (thin) ----
    gemm64_kernel<true><<<(nC + 63) / 64, 256, 0, stream>>>(x_c, nC, llw(1, 0), tb_c);
    gemm64_kernel<false><<<(nV + 63) / 64, 256, 0, stream>>>(x_v, nV, lrw(1, 0), d_out);

    // ---- final layer-1 var agg (RMW d_out) ----
    agg_rmw_kernel<<<(nV + 3) / 4, 256, 0, stream>>>(tb_c, rp_v, adj_v, llb(1, 0), (float*)d_out, nV);
}

// Round 11
// 468.487 us; speedup vs baseline: 1.1000x; 1.0433x over previous
//
#include <hip/hip_runtime.h>

#define EMB 64
#define CH 4096

// ---------------------------------------------------------------------------
// Round 11: embed_fused was the new #1 (100us var): 28% occupancy (44.5KB
// LDS -> 3 blocks/CU) + 2.63M LDS bank conflicts (stride-68 float4
// transposed stores land on 8 banks).
//  - phase-union LDS: {xs,w1s} share the 16KB weight-stage region -> 33KB
//    -> 4 blocks/CU.
//  - hs stride 65 + scalar b32 transposed stores (all-32-bank spread,
//    <=4-way); GEMM1/2 cols {c,c+16,c+32,c+48}; GEMM3/4 keep contiguous
//    cols for float4/ushort4 global writes. Bit-identical output.
//  - merged independent dispatch pairs: regroup, embed(c|v), layer-0 agg,
//    layer-1 gemm. 14 -> 9 dispatches.
// ---------------------------------------------------------------------------

static __device__ __forceinline__ unsigned short f2bf(float x) {
    union { float f; unsigned u; } v; v.f = x;
    unsigned r = v.u + 0x7fffu + ((v.u >> 16) & 1u);   // RNE
    return (unsigned short)(r >> 16);
}
static __device__ __forceinline__ float bflo(unsigned w) {
    union { unsigned u; float f; } v; v.u = w << 16; return v.f;
}
static __device__ __forceinline__ float bfhi(unsigned w) {
    union { unsigned u; float f; } v; v.u = w & 0xffff0000u; return v.f;
}

__global__ __launch_bounds__(256) void zero_int_kernel(int* __restrict__ p, int n) {
    int i = blockIdx.x * 256 + threadIdx.x;
    if (i < n) p[i] = 0;
}

__global__ __launch_bounds__(256) void bucket_hist_kernel(
    const int* __restrict__ src, const int* __restrict__ dst, int E,
    int* __restrict__ bkt_cnt_c, int* __restrict__ bkt_cnt_v,
    int shc, int shv, int NBC, int NBV)
{
    __shared__ int hc[512], hv[512];
    int t = threadIdx.x;
    int base = blockIdx.x * CH;
    int n = min(CH, E - base);
    for (int i = t; i < NBC; i += 256) hc[i] = 0;
    for (int i = t; i < NBV; i += 256) hv[i] = 0;
    __syncthreads();
    for (int li = t; li < n; li += 256) {
        atomicAdd(&hc[src[base + li] >> shc], 1);
        atomicAdd(&hv[dst[base + li] >> shv], 1);
    }
    __syncthreads();
    for (int i = t; i < NBC; i += 256) { int c = hc[i]; if (c) atomicAdd(&bkt_cnt_c[i], c); }
    for (int i = t; i < NBV; i += 256) { int c = hv[i]; if (c) atomicAdd(&bkt_cnt_v[i], c); }
}

// one block: exclusive-scan both bucket-count arrays in place; data[n] = E
__global__ __launch_bounds__(256) void scan_buckets_kernel(
    int* __restrict__ bc, int nbc, int* __restrict__ bv, int nbv, int E)
{
    __shared__ int sc[256];
    int t = threadIdx.x;
    {
        int v0 = (2 * t < nbc) ? bc[2 * t] : 0;
        int v1 = (2 * t + 1 < nbc) ? bc[2 * t + 1] : 0;
        sc[t] = v0 + v1;
        __syncthreads();
        for (int off = 1; off < 256; off <<= 1) {
            int x = (t >= off) ? sc[t - off] : 0;
            __syncthreads();
            sc[t] += x;
            __syncthreads();
        }
        int ex = (t > 0) ? sc[t - 1] : 0;
        if (2 * t < nbc) bc[2 * t] = ex;
        if (2 * t + 1 < nbc) bc[2 * t + 1] = ex + v0;
        if (t == 0) bc[nbc] = E;
        __syncthreads();
    }
    {
        int v0 = (2 * t < nbv) ? bv[2 * t] : 0;
        int v1 = (2 * t + 1 < nbv) ? bv[2 * t + 1] : 0;
        sc[t] = v0 + v1;
        __syncthreads();
        for (int off = 1; off < 256; off <<= 1) {
            int x = (t >= off) ? sc[t - off] : 0;
            __syncthreads();
            sc[t] += x;
            __syncthreads();
        }
        int ex = (t > 0) ? sc[t - 1] : 0;
        if (2 * t < nbv) bv[2 * t] = ex;
        if (2 * t + 1 < nbv) bv[2 * t + 1] = ex + v0;
        if (t == 0) bv[nbv] = E;
    }
}

// Phase 1: per-chunk LDS binning; packed u32 {local_node<<23 | other}.
__global__ __launch_bounds__(256) void bin_edges_kernel(
    const int* __restrict__ src, const int* __restrict__ dst, int E,
    const int* __restrict__ bb_c, const int* __restrict__ bb_v,
    int* __restrict__ gcur_c, int* __restrict__ gcur_v,
    unsigned* __restrict__ tmp_c, unsigned* __restrict__ tmp_v,
    int shc, int shv, int NBC, int NBV)
{
    __shared__ int hc[512], hv[512];
    int t = threadIdx.x;
    int base = blockIdx.x * CH;
    int n = min(CH, E - base);
    unsigned mc = (1u << shc) - 1u, mv = (1u << shv) - 1u;

    for (int i = t; i < NBC; i += 256) hc[i] = 0;
    for (int i = t; i < NBV; i += 256) hv[i] = 0;
    __syncthreads();

    int ss[16], dd[16];
#pragma unroll
    for (int q = 0; q < 16; ++q) {
        int li = t + q * 256;
        bool ok = li < n;
        ss[q] = ok ? src[base + li] : -1;
        dd[q] = ok ? dst[base + li] : -1;
        if (ok) {
            atomicAdd(&hc[ss[q] >> shc], 1);
            atomicAdd(&hv[dd[q] >> shv], 1);
        }
    }
    __syncthreads();

    for (int i = t; i < NBC; i += 256) {
        int c = hc[i];
        hc[i] = c ? (bb_c[i] + atomicAdd(&gcur_c[i], c)) : 0;
    }
    for (int i = t; i < NBV; i += 256) {
        int c = hv[i];
        hv[i] = c ? (bb_v[i] + atomicAdd(&gcur_v[i], c)) : 0;
    }
    __syncthreads();

#pragma unroll
    for (int q = 0; q < 16; ++q) {
        int li = t + q * 256;
        if (li < n) {
            unsigned s = (unsigned)ss[q], d = (unsigned)dd[q];
            int pc = atomicAdd(&hc[s >> shc], 1);
            tmp_c[pc] = ((s & mc) << 23) | d;
            int pv = atomicAdd(&hv[d >> shv], 1);
            tmp_v[pv] = ((d & mv) << 23) | s;
        }
    }
}

// Phase 2 (dual): wg-per-bucket over both directions in one dispatch.
__global__ __launch_bounds__(256) void regroup2_dual_kernel(
    const unsigned* __restrict__ tmpA, const int* __restrict__ bbA,
    int* __restrict__ rpA, int* __restrict__ adjA, int nAn, int shA, int nbA,
    const unsigned* __restrict__ tmpB, const int* __restrict__ bbB,
    int* __restrict__ rpB, int* __restrict__ adjB, int nBn, int shB, int nbB, int E)
{
    __shared__ int cnt[512];
    __shared__ int offs[512];
    __shared__ int sc[256];
    const unsigned* tmp; const int* bb; int* rp; int* adj; int n_nodes, sh, nb, b;
    if ((int)blockIdx.x < nbA) {
        tmp = tmpA; bb = bbA; rp = rpA; adj = adjA; n_nodes = nAn; sh = shA; nb = nbA; b = blockIdx.x;
    } else {
        tmp = tmpB; bb = bbB; rp = rpB; adj = adjB; n_nodes = nBn; sh = shB; nb = nbB; b = blockIdx.x - nbA;
    }
    int t = threadIdx.x;
    int node0 = b << sh;
    int node1 = min(node0 + (1 << sh), n_nodes);
    int nn = node1 - node0;
    for (int i = t; i < nn; i += 256) cnt[i] = 0;
    __syncthreads();
    int beg = bb[b], end = bb[b + 1];
    for (int e = beg + t; e < end; e += 256)
        atomicAdd(&cnt[tmp[e] >> 23], 1);
    __syncthreads();
    int v0 = (2 * t < nn) ? cnt[2 * t] : 0;
    int v1 = (2 * t + 1 < nn) ? cnt[2 * t + 1] : 0;
    sc[t] = v0 + v1;
    __syncthreads();
    for (int off = 1; off < 256; off <<= 1) {
        int x = (t >= off) ? sc[t - off] : 0;
        __syncthreads();
        sc[t] += x;
        __syncthreads();
    }
    int ex = (t > 0) ? sc[t - 1] : 0;
    if (2 * t < nn) offs[2 * t] = ex;
    if (2 * t + 1 < nn) offs[2 * t + 1] = ex + v0;
    __syncthreads();
    for (int i = t; i < nn; i += 256) {
        rp[node0 + i] = beg + offs[i];
        cnt[i] = 0;
    }
    if (b == nb - 1 && t == 0) rp[n_nodes] = E;
    __syncthreads();
    for (int e = beg + t; e < end; e += 256) {
        unsigned p = tmp[e];
        int d = (int)(p >> 23);
        int r = atomicAdd(&cnt[d], 1);
        adj[beg + offs[d] + r] = (int)(p & 0x7fffffu);
    }
}

// ---------------------------------------------------------------------------
// Fused node pipeline body (33KB LDS: hs[64*65] + un[4096]):
//   phase A (un = xs+w1s): GEMM1 h = relu(prenorm(x) @ W1 + b1)
//   phase B (un = w2):     GEMM2 xhat = relu(h @ W2 + b2)
//   phase C (un = wll):    GEMM3 tb = bf16(xhat @ Wll)
//   phase D (un = wlr):    GEMM4 u = xhat @ Wlr
// hs is [col][row] stride 65; scalar b32 stores (conflict-light), broadcast
// scalar reads. GEMM1/2 cols {c,c+16,c+32,c+48}; GEMM3/4 cols {4c..4c+3}.
// ---------------------------------------------------------------------------
template <int NF>
__device__ __forceinline__ void embed_body(
    float* hs, float* un,
    const float* __restrict__ x, const float* __restrict__ shift, const float* __restrict__ scale,
    const float* __restrict__ w1, const float* __restrict__ b1,
    const float* __restrict__ w2, const float* __restrict__ b2,
    const float* __restrict__ wll, const float* __restrict__ wlr,
    unsigned short* __restrict__ tb, float* __restrict__ u, int n, int bid)
{
    int t = threadIdx.x;
    long row0 = (long)bid * 64;
    int nrow = (n - row0 < 64) ? (int)(n - row0) : 64;

    float* xs  = un;             // [NF][68]
    float* w1s = un + NF * 68;   // [NF][64]

    for (int i = t; i < NF * EMB; i += 256) w1s[i] = w1[i];
    for (int i = t; i < 64 * NF; i += 256) {
        int r = i / NF, k = i - r * NF;
        float v = (r < nrow) ? x[row0 * NF + i] : 0.f;
        xs[k * 68 + r] = (v + shift[k]) * scale[k];
    }
    int r0 = (t >> 4) * 4;
    int cA = t & 15;
    float b1r[4], b2r[4];
#pragma unroll
    for (int j = 0; j < 4; ++j) { b1r[j] = b1[cA + 16 * j]; b2r[j] = b2[cA + 16 * j]; }
    __syncthreads();

    float a[4][4];
    // ---- GEMM1 ----
#pragma unroll
    for (int i = 0; i < 4; ++i)
#pragma unroll
        for (int j = 0; j < 4; ++j) a[i][j] = 0.f;
#pragma unroll
    for (int k = 0; k < NF; ++k) {
        float4 xv = *(const float4*)&xs[k * 68 + r0];
        float w0 = w1s[k * EMB + cA];
        float w1e = w1s[k * EMB + cA + 16];
        float w2e = w1s[k * EMB + cA + 32];
        float w3e = w1s[k * EMB + cA + 48];
        a[0][0] = fmaf(xv.x, w0, a[0][0]);  a[1][0] = fmaf(xv.y, w0, a[1][0]);
        a[2][0] = fmaf(xv.z, w0, a[2][0]);  a[3][0] = fmaf(xv.w, w0, a[3][0]);
        a[0][1] = fmaf(xv.x, w1e, a[0][1]); a[1][1] = fmaf(xv.y, w1e, a[1][1]);
        a[2][1] = fmaf(xv.z, w1e, a[2][1]); a[3][1] = fmaf(xv.w, w1e, a[3][1]);
        a[0][2] = fmaf(xv.x, w2e, a[0][2]); a[1][2] = fmaf(xv.y, w2e, a[1][2]);
        a[2][2] = fmaf(xv.z, w2e, a[2][2]); a[3][2] = fmaf(xv.w, w2e, a[3][2]);
        a[0][3] = fmaf(xv.x, w3e, a[0][3]); a[1][3] = fmaf(xv.y, w3e, a[1][3]);
        a[2][3] = fmaf(xv.z, w3e, a[2][3]); a[3][3] = fmaf(xv.w, w3e, a[3][3]);
    }
    __syncthreads();                    // all un (xs,w1s) reads done
    // store h -> hs; stage w2 -> un
#pragma unroll
    for (int j = 0; j < 4; ++j) {
        float* hp = &hs[(cA + 16 * j) * 65 + r0];
#pragma unroll
        for (int i = 0; i < 4; ++i) hp[i] = fmaxf(a[i][j] + b1r[j], 0.f);
    }
    {
        const float4* wg = (const float4*)w2;
        float4* wl = (float4*)un;
#pragma unroll
        for (int q = 0; q < 4; ++q) wl[t + q * 256] = wg[t + q * 256];
    }
    __syncthreads();

    // ---- GEMM2 ----
#pragma unroll
    for (int i = 0; i < 4; ++i)
#pragma unroll
        for (int j = 0; j < 4; ++j) a[i][j] = 0.f;
#pragma unroll 4
    for (int k = 0; k < EMB; ++k) {
        const float* hp = &hs[k * 65 + r0];
        float x0 = hp[0], x1 = hp[1], x2 = hp[2], x3 = hp[3];
        float w0 = un[k * EMB + cA];
        float w1e = un[k * EMB + cA + 16];
        float w2e = un[k * EMB + cA + 32];
        float w3e = un[k * EMB + cA + 48];
        a[0][0] = fmaf(x0, w0, a[0][0]);  a[1][0] = fmaf(x1, w0, a[1][0]);
        a[2][0] = fmaf(x2, w0, a[2][0]);  a[3][0] = fmaf(x3, w0, a[3][0]);
        a[0][1] = fmaf(x0, w1e, a[0][1]); a[1][1] = fmaf(x1, w1e, a[1][1]);
        a[2][1] = fmaf(x2, w1e, a[2][1]); a[3][1] = fmaf(x3, w1e, a[3][1]);
        a[0][2] = fmaf(x0, w2e, a[0][2]); a[1][2] = fmaf(x1, w2e, a[1][2]);
        a[2][2] = fmaf(x2, w2e, a[2][2]); a[3][2] = fmaf(x3, w2e, a[3][2]);
        a[0][3] = fmaf(x0, w3e, a[0][3]); a[1][3] = fmaf(x1, w3e, a[1][3]);
        a[2][3] = fmaf(x2, w3e, a[2][3]); a[3][3] = fmaf(x3, w3e, a[3][3]);
    }
    __syncthreads();                    // hs (h) + un (w2) reads done
    // store xhat -> hs; stage wll -> un
#pragma unroll
    for (int j = 0; j < 4; ++j) {
        float* hp = &hs[(cA + 16 * j) * 65 + r0];
#pragma unroll
        for (int i = 0; i < 4; ++i) hp[i] = fmaxf(a[i][j] + b2r[j], 0.f);
    }
    {
        const float4* wg = (const float4*)wll;
        float4* wl = (float4*)un;
#pragma unroll
        for (int q = 0; q < 4; ++q) wl[t + q * 256] = wg[t + q * 256];
    }
    __syncthreads();

    // ---- GEMM3: tb = bf16(xhat @ Wll), contiguous cols ----
    int c0g = (t & 15) * 4;
#pragma unroll
    for (int i = 0; i < 4; ++i)
#pragma unroll
        for (int j = 0; j < 4; ++j) a[i][j] = 0.f;
#pragma unroll 4
    for (int k = 0; k < EMB; ++k) {
        const float* hp = &hs[k * 65 + r0];
        float x0 = hp[0], x1 = hp[1], x2 = hp[2], x3 = hp[3];
        float4 wv = *(const float4*)&un[k * EMB + c0g];
        a[0][0] = fmaf(x0, wv.x, a[0][0]); a[0][1] = fmaf(x0, wv.y, a[0][1]);
        a[0][2] = fmaf(x0, wv.z, a[0][2]); a[0][3] = fmaf(x0, wv.w, a[0][3]);
        a[1][0] = fmaf(x1, wv.x, a[1][0]); a[1][1] = fmaf(x1, wv.y, a[1][1]);
        a[1][2] = fmaf(x1, wv.z, a[1][2]); a[1][3] = fmaf(x1, wv.w, a[1][3]);
        a[2][0] = fmaf(x2, wv.x, a[2][0]); a[2][1] = fmaf(x2, wv.y, a[2][1]);
        a[2][2] = fmaf(x2, wv.z, a[2][2]); a[2][3] = fmaf(x2, wv.w, a[2][3]);
        a[3][0] = fmaf(x3, wv.x, a[3][0]); a[3][1] = fmaf(x3, wv.y, a[3][1]);
        a[3][2] = fmaf(x3, wv.z, a[3][2]); a[3][3] = fmaf(x3, wv.w, a[3][3]);
    }
#pragma unroll
    for (int i = 0; i < 4; ++i) {
        long gr = row0 + r0 + i;
        if (gr < n) {
            ushort4 o;
            o.x = f2bf(a[i][0]); o.y = f2bf(a[i][1]);
            o.z = f2bf(a[i][2]); o.w = f2bf(a[i][3]);
            *(ushort4*)(tb + gr * EMB + c0g) = o;
        }
    }
    __syncthreads();                    // un (wll) reads done
    {
        const float4* wg = (const float4*)wlr;
        float4* wl = (float4*)un;
#pragma unroll
        for (int q = 0; q < 4; ++q) wl[t + q * 256] = wg[t + q * 256];
    }
    __syncthreads();

    // ---- GEMM4: u = xhat @ Wlr ----
#pragma unroll
    for (int i = 0; i < 4; ++i)
#pragma unroll
        for (int j = 0; j < 4; ++j) a[i][j] = 0.f;
#pragma unroll 4
    for (int k = 0; k < EMB; ++k) {
        const float* hp = &hs[k * 65 + r0];
        float x0 = hp[0], x1 = hp[1], x2 = hp[2], x3 = hp[3];
        float4 wv = *(const float4*)&un[k * EMB + c0g];
        a[0][0] = fmaf(x0, wv.x, a[0][0]); a[0][1] = fmaf(x0, wv.y, a[0][1]);
        a[0][2] = fmaf(x0, wv.z, a[0][2]); a[0][3] = fmaf(x0, wv.w, a[0][3]);
        a[1][0] = fmaf(x1, wv.x, a[1][0]); a[1][1] = fmaf(x1, wv.y, a[1][1]);
        a[1][2] = fmaf(x1, wv.z, a[1][2]); a[1][3] = fmaf(x1, wv.w, a[1][3]);
        a[2][0] = fmaf(x2, wv.x, a[2][0]); a[2][1] = fmaf(x2, wv.y, a[2][1]);
        a[2][2] = fmaf(x2, wv.z, a[2][2]); a[2][3] = fmaf(x2, wv.w, a[2][3]);
        a[3][0] = fmaf(x3, wv.x, a[3][0]); a[3][1] = fmaf(x3, wv.y, a[3][1]);
        a[3][2] = fmaf(x3, wv.z, a[3][2]); a[3][3] = fmaf(x3, wv.w, a[3][3]);
    }
#pragma unroll
    for (int i = 0; i < 4; ++i) {
        long gr = row0 + r0 + i;
        if (gr < n)
            *(float4*)&u[gr * EMB + c0g] = make_float4(a[i][0], a[i][1], a[i][2], a[i][3]);
    }
}

template <int NFA, int NFB>
__global__ __launch_bounds__(256) void embed_dual_kernel(
    const float* xA, const float* shA, const float* scA,
    const float* w1A, const float* b1A, const float* w2A, const float* b2A,
    const float* wllA, const float* wlrA, unsigned short* tbA, float* uA, int nA,
    const float* xB, const float* shB, const float* scB,
    const float* w1B, const float* b1B, const float* w2B, const float* b2B,
    const float* wllB, const float* wlrB, unsigned short* tbB, float* uB, int nB,
    int split)
{
    __shared__ float hs[EMB * 65];
    __shared__ float un[4096];
    if ((int)blockIdx.x < split)
        embed_body<NFA>(hs, un, xA, shA, scA, w1A, b1A, w2A, b2A, wllA, wlrA, tbA, uA, nA, blockIdx.x);
    else
        embed_body<NFB>(hs, un, xB, shB, scB, w1B, b1B, w2B, b2B, wllB, wlrB, tbB, uB, nB, blockIdx.x - split);
}

// Layer-1 GEMMs, both sides in one dispatch (A: bf16 out, B: f32 out).
__global__ __launch_bounds__(256) void gemm64_dual_kernel(
    const float* __restrict__ XA, int nA, const float* __restrict__ WA, unsigned short* __restrict__ CA,
    const float* __restrict__ XB, int nB, const float* __restrict__ WB, float* __restrict__ CB, int split)
{
    __shared__ float xs[EMB * 68];
    __shared__ float w1s[EMB * EMB];

    const float* X; const float* W; int n; int bid; bool bf;
    if ((int)blockIdx.x < split) { X = XA; W = WA; n = nA; bid = blockIdx.x; bf = true; }
    else { X = XB; W = WB; n = nB; bid = blockIdx.x - split; bf = false; }

    int t = threadIdx.x;
    {
        int r = t >> 2;
        int cs = (t & 3) * 16;
        long gr = (long)bid * 64 + r;
        float4 v[4];
        if (gr < n) {
            const float4* sp = (const float4*)(X + gr * EMB + cs);
#pragma unroll
            for (int q = 0; q < 4; ++q) v[q] = sp[q];
        } else {
            float4 z = make_float4(0.f, 0.f, 0.f, 0.f);
#pragma unroll
            for (int q = 0; q < 4; ++q) v[q] = z;
        }
#pragma unroll
        for (int q = 0; q < 4; ++q) {
            xs[(cs + q * 4 + 0) * 68 + r] = v[q].x;
            xs[(cs + q * 4 + 1) * 68 + r] = v[q].y;
            xs[(cs + q * 4 + 2) * 68 + r] = v[q].z;
            xs[(cs + q * 4 + 3) * 68 + r] = v[q].w;
        }
        const float4* wg = (const float4*)W;
        float4* wl = (float4*)w1s;
#pragma unroll
        for (int q = 0; q < 4; ++q) wl[t + q * 256] = wg[t + q * 256];
    }
    __syncthreads();

    int r0 = (t >> 4) * 4;
    int c0 = (t & 15) * 4;
    float acc[4][4] = {{0.f}};
#pragma unroll 8
    for (int k = 0; k < EMB; ++k) {
        float4 xv = *(const float4*)&xs[k * 68 + r0];
        float4 wv = *(const float4*)&w1s[k * EMB + c0];
        float xa[4] = {xv.x, xv.y, xv.z, xv.w};
        float wa[4] = {wv.x, wv.y, wv.z, wv.w};
#pragma unroll
        for (int i = 0; i < 4; ++i)
#pragma unroll
            for (int j = 0; j < 4; ++j)
                acc[i][j] = fmaf(xa[i], wa[j], acc[i][j]);
    }

#pragma unroll
    for (int i = 0; i < 4; ++i) {
        long gr = (long)bid * 64 + r0 + i;
        if (gr < n) {
            if (bf) {
                ushort4 o;
                o.x = f2bf(acc[i][0]); o.y = f2bf(acc[i][1]);
                o.z = f2bf(acc[i][2]); o.w = f2bf(acc[i][3]);
                *(ushort4*)(CA + gr * EMB + c0) = o;
            } else {
                *(float4*)(CB + gr * EMB + c0) =
                    make_float4(acc[i][0], acc[i][1], acc[i][2], acc[i][3]);
            }
        }
    }
}

// out[node] = relu(mean_nbr tb[nbr] + bias + out[node])  (RMW)
__global__ __launch_bounds__(256) void agg_rmw_kernel(
    const unsigned short* __restrict__ tbl, const int* __restrict__ rowptr,
    const int* __restrict__ adj, const float* __restrict__ bias,
    float* __restrict__ out, int n_dst)
{
    int lane = threadIdx.x & 63;
    int node = blockIdx.x * 4 + (threadIdx.x >> 6);
    if (node >= n_dst) return;
    int p = lane & 15;
    int g = lane >> 4;
    int beg = rowptr[node];
    int end = rowptr[node + 1];
    const uint2* tb = (const uint2*)tbl;
    float a0 = 0.f, a1 = 0.f, a2 = 0.f, a3 = 0.f;
    int e = beg + g;
    for (; e + 4 < end; e += 8) {
        int r0 = adj[e];
        int r1 = adj[e + 4];
        uint2 w0 = tb[(long)r0 * 16 + p];
        uint2 w1 = tb[(long)r1 * 16 + p];
        a0 += bflo(w0.x) + bflo(w1.x);
        a1 += bfhi(w0.x) + bfhi(w1.x);
        a2 += bflo(w0.y) + bflo(w1.y);
        a3 += bfhi(w0.y) + bfhi(w1.y);
    }
    if (e < end) {
        uint2 w0 = tb[(long)adj[e] * 16 + p];
        a0 += bflo(w0.x);
        a1 += bfhi(w0.x);
        a2 += bflo(w0.y);
        a3 += bfhi(w0.y);
    }
    a0 += __shfl_xor(a0, 16); a0 += __shfl_xor(a0, 32);
    a1 += __shfl_xor(a1, 16); a1 += __shfl_xor(a1, 32);
    a2 += __shfl_xor(a2, 16); a2 += __shfl_xor(a2, 32);
    a3 += __shfl_xor(a3, 16); a3 += __shfl_xor(a3, 32);
    if (g == 0) {
        int cnt = end - beg;
        float inv = 1.f / (float)(cnt > 0 ? cnt : 1);
        float4 bv = ((const float4*)bias)[p];
        float4* op = (float4*)(out + (long)node * EMB) + p;
        float4 ov = *op;
        float v0 = a0 * inv + bv.x + ov.x;
        float v1 = a1 * inv + bv.y + ov.y;
        float v2 = a2 * inv + bv.z + ov.z;
        float v3 = a3 * inv + bv.w + ov.w;
        *op = make_float4(fmaxf(v0, 0.f), fmaxf(v1, 0.f), fmaxf(v2, 0.f), fmaxf(v3, 0.f));
    }
}

// Both layer-0 aggs (independent directions) in one dispatch.
__global__ __launch_bounds__(256) void agg_rmw_dual_kernel(
    const unsigned short* __restrict__ tblA, const int* __restrict__ rpA, const int* __restrict__ adjA,
    const float* __restrict__ biasA, float* __restrict__ outA, int nA,
    const unsigned short* __restrict__ tblB, const int* __restrict__ rpB, const int* __restrict__ adjB,
    const float* __restrict__ biasB, float* __restrict__ outB, int nB, int split)
{
    const unsigned short* tbl; const int* rowptr; const int* adj; const float* bias; float* out;
    int nd, bid;
    if ((int)blockIdx.x < split) {
        tbl = tblA; rowptr = rpA; adj = adjA; bias = biasA; out = outA; nd = nA; bid = blockIdx.x;
    } else {
        tbl = tblB; rowptr = rpB; adj = adjB; bias = biasB; out = outB; nd = nB; bid = blockIdx.x - split;
    }
    int lane = threadIdx.x & 63;
    int node = bid * 4 + (threadIdx.x >> 6);
    if (node >= nd) return;
    int p = lane & 15;
    int g = lane >> 4;
    int beg = rowptr[node];
    int end = rowptr[node + 1];
    const uint2* tb = (const uint2*)tbl;
    float a0 = 0.f, a1 = 0.f, a2 = 0.f, a3 = 0.f;
    int e = beg + g;
    for (; e + 4 < end; e += 8) {
        int r0 = adj[e];
        int r1 = adj[e + 4];
        uint2 w0 = tb[(long)r0 * 16 + p];
        uint2 w1 = tb[(long)r1 * 16 + p];
        a0 += bflo(w0.x) + bflo(w1.x);
        a1 += bfhi(w0.x) + bfhi(w1.x);
        a2 += bflo(w0.y) + bflo(w1.y);
        a3 += bfhi(w0.y) + bfhi(w1.y);
    }
    if (e < end) {
        uint2 w0 = tb[(long)adj[e] * 16 + p];
        a0 += bflo(w0.x);
        a1 += bfhi(w0.x);
        a2 += bflo(w0.y);
        a3 += bfhi(w0.y);
    }
    a0 += __shfl_xor(a0, 16); a0 += __shfl_xor(a0, 32);
    a1 += __shfl_xor(a1, 16); a1 += __shfl_xor(a1, 32);
    a2 += __shfl_xor(a2, 16); a2 += __shfl_xor(a2, 32);
    a3 += __shfl_xor(a3, 16); a3 += __shfl_xor(a3, 32);
    if (g == 0) {
        int cnt = end - beg;
        float inv = 1.f / (float)(cnt > 0 ? cnt : 1);
        float4 bv = ((const float4*)bias)[p];
        float4* op = (float4*)(out + (long)node * EMB) + p;
        float4 ov = *op;
        float v0 = a0 * inv + bv.x + ov.x;
        float v1 = a1 * inv + bv.y + ov.y;
        float v2 = a2 * inv + bv.z + ov.z;
        float v3 = a3 * inv + bv.w + ov.w;
        *op = make_float4(fmaxf(v0, 0.f), fmaxf(v1, 0.f), fmaxf(v2, 0.f), fmaxf(v3, 0.f));
    }
}

extern "C" void kernel_launch(void* const* d_in, const int* in_sizes, int n_in,
                              void* d_out, int out_size, void* d_ws, size_t ws_size,
                              hipStream_t stream) {
    const float* cons_x     = (const float*)d_in[0];
    const float* var_x      = (const float*)d_in[1];
    const int*   eidx       = (const int*)d_in[3];
    const float* cons_shift = (const float*)d_in[4];
    const float* cons_scale = (const float*)d_in[5];
    const float* cons_w1    = (const float*)d_in[6];
    const float* cons_b1    = (const float*)d_in[7];
    const float* cons_w2    = (const float*)d_in[8];
    const float* cons_b2    = (const float*)d_in[9];
    const float* var_shift  = (const float*)d_in[10];
    const float* var_scale  = (const float*)d_in[11];
    const float* var_w1     = (const float*)d_in[12];
    const float* var_b1     = (const float*)d_in[13];
    const float* var_w2     = (const float*)d_in[14];
    const float* var_b2     = (const float*)d_in[15];
    const float* ll_w       = (const float*)d_in[18];
    const float* ll_b       = (const float*)d_in[19];
    const float* lr_w       = (const float*)d_in[20];

    const int nC = in_sizes[0] / 5;
    const int nV = in_sizes[1] / 19;
    const int E  = in_sizes[3] / 2;
    const int* src = eidx;       // constraint ids
    const int* dst = eidx + E;   // variable ids

    int shc = 0; while ((nC >> shc) >= 512) ++shc;
    int shv = 0; while ((nV >> shv) >= 512) ++shv;
    const int NBC = (nC + (1 << shc) - 1) >> shc;
    const int NBV = (nV + (1 << shv) - 1) >> shv;

    char* w = (char*)d_ws;
    auto alloc = [&](size_t bytes) {
        char* p = w;
        w += (bytes + 255) & ~(size_t)255;
        return p;
    };
    float* x_c = (float*)alloc((size_t)nC * EMB * 4);   // u_c, then xhat_c
    float* x_v = (float*)alloc((size_t)nV * EMB * 4);   // u_v, then xhat_v
    float* t_c = (float*)alloc((size_t)nC * EMB * 4);   // aliases: tmp_c, then bf16 table tb_c
    float* t_v = (float*)alloc((size_t)nV * EMB * 4);
    unsigned* tmp_c = (unsigned*)t_c;
    unsigned* tmp_v = (unsigned*)t_v;
    unsigned short* tb_c = (unsigned short*)t_c;
    unsigned short* tb_v = (unsigned short*)t_v;
    int* rp_v  = (int*)alloc((size_t)(nV + 1) * 4);
    int* rp_c  = (int*)alloc((size_t)(nC + 1) * 4);
    int* adj_v = (int*)alloc((size_t)E * 4);
    int* adj_c = (int*)alloc((size_t)E * 4);
    int* bkt   = (int*)alloc(4096 * 4);
    int* bb_c   = bkt;
    int* bb_v   = bkt + 1024;
    int* gcur_c = bkt + 2048;
    int* gcur_v = bkt + 3072;

    auto llw = [&](int l, int d) { return ll_w + (size_t)(l * 2 + d) * EMB * EMB; };
    auto lrw = [&](int l, int d) { return lr_w + (size_t)(l * 2 + d) * EMB * EMB; };
    auto llb = [&](int l, int d) { return ll_b + (size_t)(l * 2 + d) * EMB; };

    // ---- CSR build ----
    zero_int_kernel<<<16, 256, 0, stream>>>(bkt, 4096);
    bucket_hist_kernel<<<(E + CH - 1) / CH, 256, 0, stream>>>(src, dst, E, bb_c, bb_v, shc, shv, NBC, NBV);
    scan_buckets_kernel<<<1, 256, 0, stream>>>(bb_c, NBC, bb_v, NBV, E);
    bin_edges_kernel<<<(E + CH - 1) / CH, 256, 0, stream>>>(src, dst, E, bb_c, bb_v, gcur_c, gcur_v,
                                                            tmp_c, tmp_v, shc, shv, NBC, NBV);
    regroup2_dual_kernel<<<NBV + NBC, 256, 0, stream>>>(
        tmp_v, bb_v, rp_v, adj_v, nV, shv, NBV,
        tmp_c, bb_c, rp_c, adj_c, nC, shc, NBC, E);

    // ---- fused embed + layer-0 GEMMs, both sides in one dispatch ----
    int gc = (nC + 63) / 64, gv = (nV + 63) / 64;
    embed_dual_kernel<5, 19><<<gc + gv, 256, 0, stream>>>(
        cons_x, cons_shift, cons_scale, cons_w1, cons_b1, cons_w2, cons_b2,
        llw(0, 0), lrw(0, 1), tb_c, x_c, nC,
        var_x, var_shift, var_scale, var_w1, var_b1, var_w2, var_b2,
        llw(0, 1), lrw(0, 0), tb_v, x_v, nV,
        gc);

    // ---- layer-0 aggs (RMW u -> xhat), both directions in one dispatch ----
    int gv4 = (nV + 3) / 4, gc4 = (nC + 3) / 4;
    agg_rmw_dual_kernel<<<gv4 + gc4, 256, 0, stream>>>(
        tb_c, rp_v, adj_v, llb(0, 0), x_v, nV,
        tb_v, rp_c, adj_c, llb(0, 1), x_c, nC,
        gv4);

    // ---- layer-1 GEMMs, one dispatch ----
    gemm64_dual_kernel<<<gc + gv, 256, 0, stream>>>(
        x_c, nC, llw(1, 0), tb_c,
        x_v, nV, lrw(1, 0), (float*)d_out, gc);

    // ---- final layer-1 var agg (RMW d_out) ----
    agg_rmw_kernel<<<gv4, 256, 0, stream>>>(tb_c, rp_v, adj_v, llb(1, 0), (float*)d_out, nV);
}

// Round 12
// 441.278 us; speedup vs baseline: 1.1678x; 1.0617x over previous
//
#include <hip/hip_runtime.h>

#define EMB 64
#define CH 4096

// ---------------------------------------------------------------------------
// Round 12:
//  - embed_dual: r10 float4 GEMM structure (2 vector LDS reads/k, contiguous
//    cols) + r11 phase-union LDS (xs,w1s share staged-weight buffer) ->
//    33.4KB, 4 blocks/CU. r11's scalar rewrite fixed the wrong lever (LDS
//    instr count 4x'd); this keeps both fixes.
//  - CSR: bucket_hist deleted. bin_edges writes fixed per-bucket SLOTs with
//    global cursors; scan runs on measured counts; regroup compacts
//    slotted tmp -> packed adj/rp. Saves a full 16MB edge pass (~20us).
//  - aggs / layer-1 gemm / merges unchanged from r11.
// ---------------------------------------------------------------------------

static __device__ __forceinline__ unsigned short f2bf(float x) {
    union { float f; unsigned u; } v; v.f = x;
    unsigned r = v.u + 0x7fffu + ((v.u >> 16) & 1u);   // RNE
    return (unsigned short)(r >> 16);
}
static __device__ __forceinline__ float bflo(unsigned w) {
    union { unsigned u; float f; } v; v.u = w << 16; return v.f;
}
static __device__ __forceinline__ float bfhi(unsigned w) {
    union { unsigned u; float f; } v; v.u = w & 0xffff0000u; return v.f;
}

__global__ __launch_bounds__(256) void zero_int_kernel(int* __restrict__ p, int n) {
    int i = blockIdx.x * 256 + threadIdx.x;
    if (i < n) p[i] = 0;
}

// one block: exclusive-scan both count arrays in place (n<=512 each); data[n]=E
__global__ __launch_bounds__(256) void scan_buckets_kernel(
    int* __restrict__ bc, int nbc, int* __restrict__ bv, int nbv, int E)
{
    __shared__ int sc[256];
    int t = threadIdx.x;
    {
        int v0 = (2 * t < nbc) ? bc[2 * t] : 0;
        int v1 = (2 * t + 1 < nbc) ? bc[2 * t + 1] : 0;
        sc[t] = v0 + v1;
        __syncthreads();
        for (int off = 1; off < 256; off <<= 1) {
            int x = (t >= off) ? sc[t - off] : 0;
            __syncthreads();
            sc[t] += x;
            __syncthreads();
        }
        int ex = (t > 0) ? sc[t - 1] : 0;
        if (2 * t < nbc) bc[2 * t] = ex;
        if (2 * t + 1 < nbc) bc[2 * t + 1] = ex + v0;
        if (t == 0) bc[nbc] = E;
        __syncthreads();
    }
    {
        int v0 = (2 * t < nbv) ? bv[2 * t] : 0;
        int v1 = (2 * t + 1 < nbv) ? bv[2 * t + 1] : 0;
        sc[t] = v0 + v1;
        __syncthreads();
        for (int off = 1; off < 256; off <<= 1) {
            int x = (t >= off) ? sc[t - off] : 0;
            __syncthreads();
            sc[t] += x;
            __syncthreads();
        }
        int ex = (t > 0) ? sc[t - 1] : 0;
        if (2 * t < nbv) bv[2 * t] = ex;
        if (2 * t + 1 < nbv) bv[2 * t + 1] = ex + v0;
        if (t == 0) bv[nbv] = E;
    }
}

// Phase 1: per-chunk LDS binning into FIXED per-bucket slots (base=i*SLOT),
// global per-bucket cursors count occupancy. Packed u32 {local<<23 | other}.
__global__ __launch_bounds__(256) void bin_edges_kernel(
    const int* __restrict__ src, const int* __restrict__ dst, int E,
    int* __restrict__ gcur_c, int* __restrict__ gcur_v,
    unsigned* __restrict__ tmp_c, unsigned* __restrict__ tmp_v,
    int shc, int shv, int NBC, int NBV, int SLOTC, int SLOTV)
{
    __shared__ int hc[512], hv[512];
    int t = threadIdx.x;
    int base = blockIdx.x * CH;
    int n = min(CH, E - base);
    unsigned mc = (1u << shc) - 1u, mv = (1u << shv) - 1u;

    for (int i = t; i < NBC; i += 256) hc[i] = 0;
    for (int i = t; i < NBV; i += 256) hv[i] = 0;
    __syncthreads();

    int ss[16], dd[16];
#pragma unroll
    for (int q = 0; q < 16; ++q) {
        int li = t + q * 256;
        bool ok = li < n;
        ss[q] = ok ? src[base + li] : -1;
        dd[q] = ok ? dst[base + li] : -1;
        if (ok) {
            atomicAdd(&hc[ss[q] >> shc], 1);
            atomicAdd(&hv[dd[q] >> shv], 1);
        }
    }
    __syncthreads();

    for (int i = t; i < NBC; i += 256) {
        int c = hc[i];
        hc[i] = c ? (i * SLOTC + atomicAdd(&gcur_c[i], c)) : 0;
    }
    for (int i = t; i < NBV; i += 256) {
        int c = hv[i];
        hv[i] = c ? (i * SLOTV + atomicAdd(&gcur_v[i], c)) : 0;
    }
    __syncthreads();

#pragma unroll
    for (int q = 0; q < 16; ++q) {
        int li = t + q * 256;
        if (li < n) {
            unsigned s = (unsigned)ss[q], d = (unsigned)dd[q];
            int pc = atomicAdd(&hc[s >> shc], 1);
            tmp_c[pc] = ((s & mc) << 23) | d;
            int pv = atomicAdd(&hv[d >> shv], 1);
            tmp_v[pv] = ((d & mv) << 23) | s;
        }
    }
}

// Phase 2 (dual): wg-per-bucket; reads slotted tmp, writes packed rp/adj.
__global__ __launch_bounds__(256) void regroup2_dual_kernel(
    const unsigned* __restrict__ tmpA, const int* __restrict__ bbA,
    int* __restrict__ rpA, int* __restrict__ adjA, int nAn, int shA, int nbA, int slotA,
    const unsigned* __restrict__ tmpB, const int* __restrict__ bbB,
    int* __restrict__ rpB, int* __restrict__ adjB, int nBn, int shB, int nbB, int slotB, int E)
{
    __shared__ int cnt[512];
    __shared__ int offs[512];
    __shared__ int sc[256];
    const unsigned* tmp; const int* bb; int* rp; int* adj; int n_nodes, sh, nb, b, slot;
    if ((int)blockIdx.x < nbA) {
        tmp = tmpA; bb = bbA; rp = rpA; adj = adjA; n_nodes = nAn; sh = shA; nb = nbA; slot = slotA; b = blockIdx.x;
    } else {
        tmp = tmpB; bb = bbB; rp = rpB; adj = adjB; n_nodes = nBn; sh = shB; nb = nbB; slot = slotB; b = blockIdx.x - nbA;
    }
    int t = threadIdx.x;
    int node0 = b << sh;
    int node1 = min(node0 + (1 << sh), n_nodes);
    int nn = node1 - node0;
    for (int i = t; i < nn; i += 256) cnt[i] = 0;
    __syncthreads();
    int adjbase = bb[b];
    int cntb = bb[b + 1] - adjbase;
    int sbeg = b * slot;
    for (int e = sbeg + t; e < sbeg + cntb; e += 256)
        atomicAdd(&cnt[tmp[e] >> 23], 1);
    __syncthreads();
    int v0 = (2 * t < nn) ? cnt[2 * t] : 0;
    int v1 = (2 * t + 1 < nn) ? cnt[2 * t + 1] : 0;
    sc[t] = v0 + v1;
    __syncthreads();
    for (int off = 1; off < 256; off <<= 1) {
        int x = (t >= off) ? sc[t - off] : 0;
        __syncthreads();
        sc[t] += x;
        __syncthreads();
    }
    int ex = (t > 0) ? sc[t - 1] : 0;
    if (2 * t < nn) offs[2 * t] = ex;
    if (2 * t + 1 < nn) offs[2 * t + 1] = ex + v0;
    __syncthreads();
    for (int i = t; i < nn; i += 256) {
        rp[node0 + i] = adjbase + offs[i];
        cnt[i] = 0;
    }
    if (b == nb - 1 && t == 0) rp[n_nodes] = E;
    __syncthreads();
    for (int e = sbeg + t; e < sbeg + cntb; e += 256) {
        unsigned p = tmp[e];
        int d = (int)(p >> 23);
        int r = atomicAdd(&cnt[d], 1);
        adj[adjbase + offs[d] + r] = (int)(p & 0x7fffffu);
    }
}

// ---------------------------------------------------------------------------
// Fused node pipeline body (33.4KB LDS: hs[64*68] + un[4096]):
//   phase A (un = xs+w1s): GEMM1 h = relu(prenorm(x) @ W1 + b1)
//   phase B (un = w2):     GEMM2 xhat = relu(h @ W2 + b2)
//   phase C (un = wll):    GEMM3 tb = bf16(xhat @ Wll)
//   phase D (un = wlr):    GEMM4 u = xhat @ Wlr
// hs transposed [col][row] stride 68 (float4-aligned); all GEMMs read
// x: 1x ds_read_b128, w: 1x ds_read_b128 per k. Contiguous cols c0=4*(t&15).
// ---------------------------------------------------------------------------
template <int NF>
__device__ __forceinline__ void embed_body(
    float* hs, float* un,
    const float* __restrict__ x, const float* __restrict__ shift, const float* __restrict__ scale,
    const float* __restrict__ w1, const float* __restrict__ b1,
    const float* __restrict__ w2, const float* __restrict__ b2,
    const float* __restrict__ wll, const float* __restrict__ wlr,
    unsigned short* __restrict__ tb, float* __restrict__ u, int n, int bid)
{
    int t = threadIdx.x;
    long row0 = (long)bid * 64;
    int nrow = (n - row0 < 64) ? (int)(n - row0) : 64;

    float* xs  = un;             // [NF][68] (transposed, prenormed)
    float* w1s = un + NF * 68;   // [NF][64]

    for (int i = t; i < NF * EMB; i += 256) w1s[i] = w1[i];
    for (int i = t; i < 64 * NF; i += 256) {
        int r = i / NF, k = i - r * NF;
        float v = (r < nrow) ? x[row0 * NF + i] : 0.f;
        xs[k * 68 + r] = (v + shift[k]) * scale[k];
    }
    int r0 = (t >> 4) * 4;
    int c0 = (t & 15) * 4;
    float4 b1v = *(const float4*)&b1[c0];
    float4 b2v = *(const float4*)&b2[c0];
    __syncthreads();

    float a[4][4];
    // ---- GEMM1 ----
#pragma unroll
    for (int i = 0; i < 4; ++i)
#pragma unroll
        for (int j = 0; j < 4; ++j) a[i][j] = 0.f;
#pragma unroll
    for (int k = 0; k < NF; ++k) {
        float4 xv = *(const float4*)&xs[k * 68 + r0];
        float4 wv = *(const float4*)&w1s[k * EMB + c0];
        float xa[4] = {xv.x, xv.y, xv.z, xv.w};
        float wa[4] = {wv.x, wv.y, wv.z, wv.w};
#pragma unroll
        for (int i = 0; i < 4; ++i)
#pragma unroll
            for (int j = 0; j < 4; ++j)
                a[i][j] = fmaf(xa[i], wa[j], a[i][j]);
    }
    __syncthreads();                    // un (xs,w1s) reads complete
    // h -> hs transposed; stage w2 -> un
    {
        float ba[4] = {b1v.x, b1v.y, b1v.z, b1v.w};
#pragma unroll
        for (int j = 0; j < 4; ++j) {
            float4 o;
            o.x = fmaxf(a[0][j] + ba[j], 0.f);
            o.y = fmaxf(a[1][j] + ba[j], 0.f);
            o.z = fmaxf(a[2][j] + ba[j], 0.f);
            o.w = fmaxf(a[3][j] + ba[j], 0.f);
            *(float4*)&hs[(c0 + j) * 68 + r0] = o;
        }
    }
    {
        const float4* wg = (const float4*)w2;
        float4* wl = (float4*)un;
#pragma unroll
        for (int q = 0; q < 4; ++q) wl[t + q * 256] = wg[t + q * 256];
    }
    __syncthreads();

    // ---- GEMM2 ----
#pragma unroll
    for (int i = 0; i < 4; ++i)
#pragma unroll
        for (int j = 0; j < 4; ++j) a[i][j] = 0.f;
#pragma unroll 8
    for (int k = 0; k < EMB; ++k) {
        float4 xv = *(const float4*)&hs[k * 68 + r0];
        float4 wv = *(const float4*)&un[k * EMB + c0];
        float xa[4] = {xv.x, xv.y, xv.z, xv.w};
        float wa[4] = {wv.x, wv.y, wv.z, wv.w};
#pragma unroll
        for (int i = 0; i < 4; ++i)
#pragma unroll
            for (int j = 0; j < 4; ++j)
                a[i][j] = fmaf(xa[i], wa[j], a[i][j]);
    }
    __syncthreads();                    // hs (h) + un (w2) reads complete
    // xhat -> hs transposed; stage wll -> un
    {
        float ba[4] = {b2v.x, b2v.y, b2v.z, b2v.w};
#pragma unroll
        for (int j = 0; j < 4; ++j) {
            float4 o;
            o.x = fmaxf(a[0][j] + ba[j], 0.f);
            o.y = fmaxf(a[1][j] + ba[j], 0.f);
            o.z = fmaxf(a[2][j] + ba[j], 0.f);
            o.w = fmaxf(a[3][j] + ba[j], 0.f);
            *(float4*)&hs[(c0 + j) * 68 + r0] = o;
        }
    }
    {
        const float4* wg = (const float4*)wll;
        float4* wl = (float4*)un;
#pragma unroll
        for (int q = 0; q < 4; ++q) wl[t + q * 256] = wg[t + q * 256];
    }
    __syncthreads();

    // ---- GEMM3: tb = bf16(xhat @ Wll) ----
#pragma unroll
    for (int i = 0; i < 4; ++i)
#pragma unroll
        for (int j = 0; j < 4; ++j) a[i][j] = 0.f;
#pragma unroll 8
    for (int k = 0; k < EMB; ++k) {
        float4 xv = *(const float4*)&hs[k * 68 + r0];
        float4 wv = *(const float4*)&un[k * EMB + c0];
        float xa[4] = {xv.x, xv.y, xv.z, xv.w};
        float wa[4] = {wv.x, wv.y, wv.z, wv.w};
#pragma unroll
        for (int i = 0; i < 4; ++i)
#pragma unroll
            for (int j = 0; j < 4; ++j)
                a[i][j] = fmaf(xa[i], wa[j], a[i][j]);
    }
    __syncthreads();                    // un (wll) reads complete
    {
        const float4* wg = (const float4*)wlr;
        float4* wl = (float4*)un;
#pragma unroll
        for (int q = 0; q < 4; ++q) wl[t + q * 256] = wg[t + q * 256];
    }
#pragma unroll
    for (int i = 0; i < 4; ++i) {
        long gr = row0 + r0 + i;
        if (gr < n) {
            ushort4 o;
            o.x = f2bf(a[i][0]); o.y = f2bf(a[i][1]);
            o.z = f2bf(a[i][2]); o.w = f2bf(a[i][3]);
            *(ushort4*)(tb + gr * EMB + c0) = o;
        }
    }
    __syncthreads();

    // ---- GEMM4: u = xhat @ Wlr ----
#pragma unroll
    for (int i = 0; i < 4; ++i)
#pragma unroll
        for (int j = 0; j < 4; ++j) a[i][j] = 0.f;
#pragma unroll 8
    for (int k = 0; k < EMB; ++k) {
        float4 xv = *(const float4*)&hs[k * 68 + r0];
        float4 wv = *(const float4*)&un[k * EMB + c0];
        float xa[4] = {xv.x, xv.y, xv.z, xv.w};
        float wa[4] = {wv.x, wv.y, wv.z, wv.w};
#pragma unroll
        for (int i = 0; i < 4; ++i)
#pragma unroll
            for (int j = 0; j < 4; ++j)
                a[i][j] = fmaf(xa[i], wa[j], a[i][j]);
    }
#pragma unroll
    for (int i = 0; i < 4; ++i) {
        long gr = row0 + r0 + i;
        if (gr < n)
            *(float4*)&u[gr * EMB + c0] = make_float4(a[i][0], a[i][1], a[i][2], a[i][3]);
    }
}

template <int NFA, int NFB>
__global__ __launch_bounds__(256) void embed_dual_kernel(
    const float* xA, const float* shA, const float* scA,
    const float* w1A, const float* b1A, const float* w2A, const float* b2A,
    const float* wllA, const float* wlrA, unsigned short* tbA, float* uA, int nA,
    const float* xB, const float* shB, const float* scB,
    const float* w1B, const float* b1B, const float* w2B, const float* b2B,
    const float* wllB, const float* wlrB, unsigned short* tbB, float* uB, int nB,
    int split)
{
    __shared__ __align__(16) float hs[EMB * 68];
    __shared__ __align__(16) float un[4096];
    if ((int)blockIdx.x < split)
        embed_body<NFA>(hs, un, xA, shA, scA, w1A, b1A, w2A, b2A, wllA, wlrA, tbA, uA, nA, blockIdx.x);
    else
        embed_body<NFB>(hs, un, xB, shB, scB, w1B, b1B, w2B, b2B, wllB, wlrB, tbB, uB, nB, blockIdx.x - split);
}

// Layer-1 GEMMs, both sides in one dispatch (A: bf16 out, B: f32 out).
__global__ __launch_bounds__(256) void gemm64_dual_kernel(
    const float* __restrict__ XA, int nA, const float* __restrict__ WA, unsigned short* __restrict__ CA,
    const float* __restrict__ XB, int nB, const float* __restrict__ WB, float* __restrict__ CB, int split)
{
    __shared__ __align__(16) float xs[EMB * 68];
    __shared__ __align__(16) float w1s[EMB * EMB];

    const float* X; const float* W; int n; int bid; bool bf;
    if ((int)blockIdx.x < split) { X = XA; W = WA; n = nA; bid = blockIdx.x; bf = true; }
    else { X = XB; W = WB; n = nB; bid = blockIdx.x - split; bf = false; }

    int t = threadIdx.x;
    {
        int r = t >> 2;
        int cs = (t & 3) * 16;
        long gr = (long)bid * 64 + r;
        float4 v[4];
        if (gr < n) {
            const float4* sp = (const float4*)(X + gr * EMB + cs);
#pragma unroll
            for (int q = 0; q < 4; ++q) v[q] = sp[q];
        } else {
            float4 z = make_float4(0.f, 0.f, 0.f, 0.f);
#pragma unroll
            for (int q = 0; q < 4; ++q) v[q] = z;
        }
#pragma unroll
        for (int q = 0; q < 4; ++q) {
            xs[(cs + q * 4 + 0) * 68 + r] = v[q].x;
            xs[(cs + q * 4 + 1) * 68 + r] = v[q].y;
            xs[(cs + q * 4 + 2) * 68 + r] = v[q].z;
            xs[(cs + q * 4 + 3) * 68 + r] = v[q].w;
        }
        const float4* wg = (const float4*)W;
        float4* wl = (float4*)w1s;
#pragma unroll
        for (int q = 0; q < 4; ++q) wl[t + q * 256] = wg[t + q * 256];
    }
    __syncthreads();

    int r0 = (t >> 4) * 4;
    int c0 = (t & 15) * 4;
    float acc[4][4] = {{0.f}};
#pragma unroll 8
    for (int k = 0; k < EMB; ++k) {
        float4 xv = *(const float4*)&xs[k * 68 + r0];
        float4 wv = *(const float4*)&w1s[k * EMB + c0];
        float xa[4] = {xv.x, xv.y, xv.z, xv.w};
        float wa[4] = {wv.x, wv.y, wv.z, wv.w};
#pragma unroll
        for (int i = 0; i < 4; ++i)
#pragma unroll
            for (int j = 0; j < 4; ++j)
                acc[i][j] = fmaf(xa[i], wa[j], acc[i][j]);
    }

#pragma unroll
    for (int i = 0; i < 4; ++i) {
        long gr = (long)bid * 64 + r0 + i;
        if (gr < n) {
            if (bf) {
                ushort4 o;
                o.x = f2bf(acc[i][0]); o.y = f2bf(acc[i][1]);
                o.z = f2bf(acc[i][2]); o.w = f2bf(acc[i][3]);
                *(ushort4*)(CA + gr * EMB + c0) = o;
            } else {
                *(float4*)(CB + gr * EMB + c0) =
                    make_float4(acc[i][0], acc[i][1], acc[i][2], acc[i][3]);
            }
        }
    }
}

// out[node] = relu(mean_nbr tb[nbr] + bias + out[node])  (RMW)
__global__ __launch_bounds__(256) void agg_rmw_kernel(
    const unsigned short* __restrict__ tbl, const int* __restrict__ rowptr,
    const int* __restrict__ adj, const float* __restrict__ bias,
    float* __restrict__ out, int n_dst)
{
    int lane = threadIdx.x & 63;
    int node = blockIdx.x * 4 + (threadIdx.x >> 6);
    if (node >= n_dst) return;
    int p = lane & 15;
    int g = lane >> 4;
    int beg = rowptr[node];
    int end = rowptr[node + 1];
    const uint2* tb = (const uint2*)tbl;
    float a0 = 0.f, a1 = 0.f, a2 = 0.f, a3 = 0.f;
    int e = beg + g;
    for (; e + 4 < end; e += 8) {
        int r0 = adj[e];
        int r1 = adj[e + 4];
        uint2 w0 = tb[(long)r0 * 16 + p];
        uint2 w1 = tb[(long)r1 * 16 + p];
        a0 += bflo(w0.x) + bflo(w1.x);
        a1 += bfhi(w0.x) + bfhi(w1.x);
        a2 += bflo(w0.y) + bflo(w1.y);
        a3 += bfhi(w0.y) + bfhi(w1.y);
    }
    if (e < end) {
        uint2 w0 = tb[(long)adj[e] * 16 + p];
        a0 += bflo(w0.x);
        a1 += bfhi(w0.x);
        a2 += bflo(w0.y);
        a3 += bfhi(w0.y);
    }
    a0 += __shfl_xor(a0, 16); a0 += __shfl_xor(a0, 32);
    a1 += __shfl_xor(a1, 16); a1 += __shfl_xor(a1, 32);
    a2 += __shfl_xor(a2, 16); a2 += __shfl_xor(a2, 32);
    a3 += __shfl_xor(a3, 16); a3 += __shfl_xor(a3, 32);
    if (g == 0) {
        int cnt = end - beg;
        float inv = 1.f / (float)(cnt > 0 ? cnt : 1);
        float4 bv = ((const float4*)bias)[p];
        float4* op = (float4*)(out + (long)node * EMB) + p;
        float4 ov = *op;
        float v0 = a0 * inv + bv.x + ov.x;
        float v1 = a1 * inv + bv.y + ov.y;
        float v2 = a2 * inv + bv.z + ov.z;
        float v3 = a3 * inv + bv.w + ov.w;
        *op = make_float4(fmaxf(v0, 0.f), fmaxf(v1, 0.f), fmaxf(v2, 0.f), fmaxf(v3, 0.f));
    }
}

// Both layer-0 aggs (independent directions) in one dispatch.
__global__ __launch_bounds__(256) void agg_rmw_dual_kernel(
    const unsigned short* __restrict__ tblA, const int* __restrict__ rpA, const int* __restrict__ adjA,
    const float* __restrict__ biasA, float* __restrict__ outA, int nA,
    const unsigned short* __restrict__ tblB, const int* __restrict__ rpB, const int* __restrict__ adjB,
    const float* __restrict__ biasB, float* __restrict__ outB, int nB, int split)
{
    const unsigned short* tbl; const int* rowptr; const int* adj; const float* bias; float* out;
    int nd, bid;
    if ((int)blockIdx.x < split) {
        tbl = tblA; rowptr = rpA; adj = adjA; bias = biasA; out = outA; nd = nA; bid = blockIdx.x;
    } else {
        tbl = tblB; rowptr = rpB; adj = adjB; bias = biasB; out = outB; nd = nB; bid = blockIdx.x - split;
    }
    int lane = threadIdx.x & 63;
    int node = bid * 4 + (threadIdx.x >> 6);
    if (node >= nd) return;
    int p = lane & 15;
    int g = lane >> 4;
    int beg = rowptr[node];
    int end = rowptr[node + 1];
    const uint2* tb = (const uint2*)tbl;
    float a0 = 0.f, a1 = 0.f, a2 = 0.f, a3 = 0.f;
    int e = beg + g;
    for (; e + 4 < end; e += 8) {
        int r0 = adj[e];
        int r1 = adj[e + 4];
        uint2 w0 = tb[(long)r0 * 16 + p];
        uint2 w1 = tb[(long)r1 * 16 + p];
        a0 += bflo(w0.x) + bflo(w1.x);
        a1 += bfhi(w0.x) + bfhi(w1.x);
        a2 += bflo(w0.y) + bflo(w1.y);
        a3 += bfhi(w0.y) + bfhi(w1.y);
    }
    if (e < end) {
        uint2 w0 = tb[(long)adj[e] * 16 + p];
        a0 += bflo(w0.x);
        a1 += bfhi(w0.x);
        a2 += bflo(w0.y);
        a3 += bfhi(w0.y);
    }
    a0 += __shfl_xor(a0, 16); a0 += __shfl_xor(a0, 32);
    a1 += __shfl_xor(a1, 16); a1 += __shfl_xor(a1, 32);
    a2 += __shfl_xor(a2, 16); a2 += __shfl_xor(a2, 32);
    a3 += __shfl_xor(a3, 16); a3 += __shfl_xor(a3, 32);
    if (g == 0) {
        int cnt = end - beg;
        float inv = 1.f / (float)(cnt > 0 ? cnt : 1);
        float4 bv = ((const float4*)bias)[p];
        float4* op = (float4*)(out + (long)node * EMB) + p;
        float4 ov = *op;
        float v0 = a0 * inv + bv.x + ov.x;
        float v1 = a1 * inv + bv.y + ov.y;
        float v2 = a2 * inv + bv.z + ov.z;
        float v3 = a3 * inv + bv.w + ov.w;
        *op = make_float4(fmaxf(v0, 0.f), fmaxf(v1, 0.f), fmaxf(v2, 0.f), fmaxf(v3, 0.f));
    }
}

extern "C" void kernel_launch(void* const* d_in, const int* in_sizes, int n_in,
                              void* d_out, int out_size, void* d_ws, size_t ws_size,
                              hipStream_t stream) {
    const float* cons_x     = (const float*)d_in[0];
    const float* var_x      = (const float*)d_in[1];
    const int*   eidx       = (const int*)d_in[3];
    const float* cons_shift = (const float*)d_in[4];
    const float* cons_scale = (const float*)d_in[5];
    const float* cons_w1    = (const float*)d_in[6];
    const float* cons_b1    = (const float*)d_in[7];
    const float* cons_w2    = (const float*)d_in[8];
    const float* cons_b2    = (const float*)d_in[9];
    const float* var_shift  = (const float*)d_in[10];
    const float* var_scale  = (const float*)d_in[11];
    const float* var_w1     = (const float*)d_in[12];
    const float* var_b1     = (const float*)d_in[13];
    const float* var_w2     = (const float*)d_in[14];
    const float* var_b2     = (const float*)d_in[15];
    const float* ll_w       = (const float*)d_in[18];
    const float* ll_b       = (const float*)d_in[19];
    const float* lr_w       = (const float*)d_in[20];

    const int nC = in_sizes[0] / 5;
    const int nV = in_sizes[1] / 19;
    const int E  = in_sizes[3] / 2;
    const int* src = eidx;       // constraint ids
    const int* dst = eidx + E;   // variable ids

    int shc = 0; while ((nC >> shc) >= 512) ++shc;
    int shv = 0; while ((nV >> shv) >= 512) ++shv;
    const int NBC = (nC + (1 << shc) - 1) >> shc;
    const int NBV = (nV + (1 << shv) - 1) >> shv;

    char* w = (char*)d_ws;
    auto alloc = [&](size_t bytes) {
        char* p = w;
        w += (bytes + 255) & ~(size_t)255;
        return p;
    };
    float* x_c = (float*)alloc((size_t)nC * EMB * 4);   // u_c, then xhat_c
    float* x_v = (float*)alloc((size_t)nV * EMB * 4);   // u_v, then xhat_v
    float* t_c = (float*)alloc((size_t)nC * EMB * 4);   // aliases: slotted tmp_c, then bf16 tb_c
    float* t_v = (float*)alloc((size_t)nV * EMB * 4);
    unsigned* tmp_c = (unsigned*)t_c;
    unsigned* tmp_v = (unsigned*)t_v;
    unsigned short* tb_c = (unsigned short*)t_c;
    unsigned short* tb_v = (unsigned short*)t_v;
    int* rp_v  = (int*)alloc((size_t)(nV + 1) * 4);
    int* rp_c  = (int*)alloc((size_t)(nC + 1) * 4);
    int* adj_v = (int*)alloc((size_t)E * 4);
    int* adj_c = (int*)alloc((size_t)E * 4);
    int* bkt   = (int*)alloc(2048 * 4);
    int* gcur_c = bkt;            // counts, then exclusive bases (NBC+1)
    int* gcur_v = bkt + 1024;     // counts, then exclusive bases (NBV+1)

    // fixed per-bucket slots in tmp (2x mean, clamped to region capacity)
    auto slot_for = [&](int NB, size_t cap_ints) {
        long s = 2L * E / NB;
        s = (s + 255) & ~255L;
        if (s < 4096) s = 4096;
        long cap = (long)(cap_ints / NB) & ~255L;
        if (s > cap) s = cap;
        return (int)s;
    };
    const int SLOTC = slot_for(NBC, (size_t)nC * EMB);
    const int SLOTV = slot_for(NBV, (size_t)nV * EMB);

    auto llw = [&](int l, int d) { return ll_w + (size_t)(l * 2 + d) * EMB * EMB; };
    auto lrw = [&](int l, int d) { return lr_w + (size_t)(l * 2 + d) * EMB * EMB; };
    auto llb = [&](int l, int d) { return ll_b + (size_t)(l * 2 + d) * EMB; };

    // ---- CSR build (no histogram pass: fixed slots + post-scan) ----
    zero_int_kernel<<<8, 256, 0, stream>>>(bkt, 2048);
    bin_edges_kernel<<<(E + CH - 1) / CH, 256, 0, stream>>>(src, dst, E, gcur_c, gcur_v,
                                                            tmp_c, tmp_v, shc, shv, NBC, NBV,
                                                            SLOTC, SLOTV);
    scan_buckets_kernel<<<1, 256, 0, stream>>>(gcur_c, NBC, gcur_v, NBV, E);
    regroup2_dual_kernel<<<NBV + NBC, 256, 0, stream>>>(
        tmp_v, gcur_v, rp_v, adj_v, nV, shv, NBV, SLOTV,
        tmp_c, gcur_c, rp_c, adj_c, nC, shc, NBC, SLOTC, E);

    // ---- fused embed + layer-0 GEMMs, both sides in one dispatch ----
    int gc = (nC + 63) / 64, gv = (nV + 63) / 64;
    embed_dual_kernel<5, 19><<<gc + gv, 256, 0, stream>>>(
        cons_x, cons_shift, cons_scale, cons_w1, cons_b1, cons_w2, cons_b2,
        llw(0, 0), lrw(0, 1), tb_c, x_c, nC,
        var_x, var_shift, var_scale, var_w1, var_b1, var_w2, var_b2,
        llw(0, 1), lrw(0, 0), tb_v, x_v, nV,
        gc);

    // ---- layer-0 aggs (RMW u -> xhat), both directions in one dispatch ----
    int gv4 = (nV + 3) / 4, gc4 = (nC + 3) / 4;
    agg_rmw_dual_kernel<<<gv4 + gc4, 256, 0, stream>>>(
        tb_c, rp_v, adj_v, llb(0, 0), x_v, nV,
        tb_v, rp_c, adj_c, llb(0, 1), x_c, nC,
        gv4);

    // ---- layer-1 GEMMs, one dispatch ----
    gemm64_dual_kernel<<<gc + gv, 256, 0, stream>>>(
        x_c, nC, llw(1, 0), tb_c,
        x_v, nV, lrw(1, 0), (float*)d_out, gc);

    // ---- final layer-1 var agg (RMW d_out) ----
    agg_rmw_kernel<<<gv4, 256, 0, stream>>>(tb_c, rp_v, adj_v, llb(1, 0), (float*)d_out, nV);
}

// Round 13
// 439.330 us; speedup vs baseline: 1.1730x; 1.0044x over previous
//
#include <hip/hip_runtime.h>

#define EMB 64
#define CH 4096

// ---------------------------------------------------------------------------
// Round 13:
//  - de-merge layer-0 aggs (r12's dual ran tb_c+tb_v = 38.4MB gather set
//    against 32MB L2 -> thrash; separate = each table L2-resident-ish).
//  - agg gather widened to 16B/lane (uint4 = 8 bf16): lane = (oct p in [0,8),
//    slot g in [0,8)); one wave load = 8 rows = 1KB; unroll 2 -> 16 rows in
//    flight; half the loop iters + memory instructions of the 8B version.
//    shfl_xor(8,16,32) reduce; g==0 lanes RMW 2x float4.
//  - rest unchanged from r12 (fused embed, slotted CSR, dual gemm).
// ---------------------------------------------------------------------------

static __device__ __forceinline__ unsigned short f2bf(float x) {
    union { float f; unsigned u; } v; v.f = x;
    unsigned r = v.u + 0x7fffu + ((v.u >> 16) & 1u);   // RNE
    return (unsigned short)(r >> 16);
}
static __device__ __forceinline__ float bflo(unsigned w) {
    union { unsigned u; float f; } v; v.u = w << 16; return v.f;
}
static __device__ __forceinline__ float bfhi(unsigned w) {
    union { unsigned u; float f; } v; v.u = w & 0xffff0000u; return v.f;
}

__global__ __launch_bounds__(256) void zero_int_kernel(int* __restrict__ p, int n) {
    int i = blockIdx.x * 256 + threadIdx.x;
    if (i < n) p[i] = 0;
}

// one block: exclusive-scan both count arrays in place (n<=512 each); data[n]=E
__global__ __launch_bounds__(256) void scan_buckets_kernel(
    int* __restrict__ bc, int nbc, int* __restrict__ bv, int nbv, int E)
{
    __shared__ int sc[256];
    int t = threadIdx.x;
    {
        int v0 = (2 * t < nbc) ? bc[2 * t] : 0;
        int v1 = (2 * t + 1 < nbc) ? bc[2 * t + 1] : 0;
        sc[t] = v0 + v1;
        __syncthreads();
        for (int off = 1; off < 256; off <<= 1) {
            int x = (t >= off) ? sc[t - off] : 0;
            __syncthreads();
            sc[t] += x;
            __syncthreads();
        }
        int ex = (t > 0) ? sc[t - 1] : 0;
        if (2 * t < nbc) bc[2 * t] = ex;
        if (2 * t + 1 < nbc) bc[2 * t + 1] = ex + v0;
        if (t == 0) bc[nbc] = E;
        __syncthreads();
    }
    {
        int v0 = (2 * t < nbv) ? bv[2 * t] : 0;
        int v1 = (2 * t + 1 < nbv) ? bv[2 * t + 1] : 0;
        sc[t] = v0 + v1;
        __syncthreads();
        for (int off = 1; off < 256; off <<= 1) {
            int x = (t >= off) ? sc[t - off] : 0;
            __syncthreads();
            sc[t] += x;
            __syncthreads();
        }
        int ex = (t > 0) ? sc[t - 1] : 0;
        if (2 * t < nbv) bv[2 * t] = ex;
        if (2 * t + 1 < nbv) bv[2 * t + 1] = ex + v0;
        if (t == 0) bv[nbv] = E;
    }
}

// Phase 1: per-chunk LDS binning into FIXED per-bucket slots (base=i*SLOT),
// global per-bucket cursors count occupancy. Packed u32 {local<<23 | other}.
__global__ __launch_bounds__(256) void bin_edges_kernel(
    const int* __restrict__ src, const int* __restrict__ dst, int E,
    int* __restrict__ gcur_c, int* __restrict__ gcur_v,
    unsigned* __restrict__ tmp_c, unsigned* __restrict__ tmp_v,
    int shc, int shv, int NBC, int NBV, int SLOTC, int SLOTV)
{
    __shared__ int hc[512], hv[512];
    int t = threadIdx.x;
    int base = blockIdx.x * CH;
    int n = min(CH, E - base);
    unsigned mc = (1u << shc) - 1u, mv = (1u << shv) - 1u;

    for (int i = t; i < NBC; i += 256) hc[i] = 0;
    for (int i = t; i < NBV; i += 256) hv[i] = 0;
    __syncthreads();

    int ss[16], dd[16];
#pragma unroll
    for (int q = 0; q < 16; ++q) {
        int li = t + q * 256;
        bool ok = li < n;
        ss[q] = ok ? src[base + li] : -1;
        dd[q] = ok ? dst[base + li] : -1;
        if (ok) {
            atomicAdd(&hc[ss[q] >> shc], 1);
            atomicAdd(&hv[dd[q] >> shv], 1);
        }
    }
    __syncthreads();

    for (int i = t; i < NBC; i += 256) {
        int c = hc[i];
        hc[i] = c ? (i * SLOTC + atomicAdd(&gcur_c[i], c)) : 0;
    }
    for (int i = t; i < NBV; i += 256) {
        int c = hv[i];
        hv[i] = c ? (i * SLOTV + atomicAdd(&gcur_v[i], c)) : 0;
    }
    __syncthreads();

#pragma unroll
    for (int q = 0; q < 16; ++q) {
        int li = t + q * 256;
        if (li < n) {
            unsigned s = (unsigned)ss[q], d = (unsigned)dd[q];
            int pc = atomicAdd(&hc[s >> shc], 1);
            tmp_c[pc] = ((s & mc) << 23) | d;
            int pv = atomicAdd(&hv[d >> shv], 1);
            tmp_v[pv] = ((d & mv) << 23) | s;
        }
    }
}

// Phase 2 (dual): wg-per-bucket; reads slotted tmp, writes packed rp/adj.
__global__ __launch_bounds__(256) void regroup2_dual_kernel(
    const unsigned* __restrict__ tmpA, const int* __restrict__ bbA,
    int* __restrict__ rpA, int* __restrict__ adjA, int nAn, int shA, int nbA, int slotA,
    const unsigned* __restrict__ tmpB, const int* __restrict__ bbB,
    int* __restrict__ rpB, int* __restrict__ adjB, int nBn, int shB, int nbB, int slotB, int E)
{
    __shared__ int cnt[512];
    __shared__ int offs[512];
    __shared__ int sc[256];
    const unsigned* tmp; const int* bb; int* rp; int* adj; int n_nodes, sh, nb, b, slot;
    if ((int)blockIdx.x < nbA) {
        tmp = tmpA; bb = bbA; rp = rpA; adj = adjA; n_nodes = nAn; sh = shA; nb = nbA; slot = slotA; b = blockIdx.x;
    } else {
        tmp = tmpB; bb = bbB; rp = rpB; adj = adjB; n_nodes = nBn; sh = shB; nb = nbB; slot = slotB; b = blockIdx.x - nbA;
    }
    int t = threadIdx.x;
    int node0 = b << sh;
    int node1 = min(node0 + (1 << sh), n_nodes);
    int nn = node1 - node0;
    for (int i = t; i < nn; i += 256) cnt[i] = 0;
    __syncthreads();
    int adjbase = bb[b];
    int cntb = bb[b + 1] - adjbase;
    int sbeg = b * slot;
    for (int e = sbeg + t; e < sbeg + cntb; e += 256)
        atomicAdd(&cnt[tmp[e] >> 23], 1);
    __syncthreads();
    int v0 = (2 * t < nn) ? cnt[2 * t] : 0;
    int v1 = (2 * t + 1 < nn) ? cnt[2 * t + 1] : 0;
    sc[t] = v0 + v1;
    __syncthreads();
    for (int off = 1; off < 256; off <<= 1) {
        int x = (t >= off) ? sc[t - off] : 0;
        __syncthreads();
        sc[t] += x;
        __syncthreads();
    }
    int ex = (t > 0) ? sc[t - 1] : 0;
    if (2 * t < nn) offs[2 * t] = ex;
    if (2 * t + 1 < nn) offs[2 * t + 1] = ex + v0;
    __syncthreads();
    for (int i = t; i < nn; i += 256) {
        rp[node0 + i] = adjbase + offs[i];
        cnt[i] = 0;
    }
    if (b == nb - 1 && t == 0) rp[n_nodes] = E;
    __syncthreads();
    for (int e = sbeg + t; e < sbeg + cntb; e += 256) {
        unsigned p = tmp[e];
        int d = (int)(p >> 23);
        int r = atomicAdd(&cnt[d], 1);
        adj[adjbase + offs[d] + r] = (int)(p & 0x7fffffu);
    }
}

// ---------------------------------------------------------------------------
// Fused node pipeline body (33.4KB LDS: hs[64*68] + un[4096]).
// ---------------------------------------------------------------------------
template <int NF>
__device__ __forceinline__ void embed_body(
    float* hs, float* un,
    const float* __restrict__ x, const float* __restrict__ shift, const float* __restrict__ scale,
    const float* __restrict__ w1, const float* __restrict__ b1,
    const float* __restrict__ w2, const float* __restrict__ b2,
    const float* __restrict__ wll, const float* __restrict__ wlr,
    unsigned short* __restrict__ tb, float* __restrict__ u, int n, int bid)
{
    int t = threadIdx.x;
    long row0 = (long)bid * 64;
    int nrow = (n - row0 < 64) ? (int)(n - row0) : 64;

    float* xs  = un;             // [NF][68] (transposed, prenormed)
    float* w1s = un + NF * 68;   // [NF][64]

    for (int i = t; i < NF * EMB; i += 256) w1s[i] = w1[i];
    for (int i = t; i < 64 * NF; i += 256) {
        int r = i / NF, k = i - r * NF;
        float v = (r < nrow) ? x[row0 * NF + i] : 0.f;
        xs[k * 68 + r] = (v + shift[k]) * scale[k];
    }
    int r0 = (t >> 4) * 4;
    int c0 = (t & 15) * 4;
    float4 b1v = *(const float4*)&b1[c0];
    float4 b2v = *(const float4*)&b2[c0];
    __syncthreads();

    float a[4][4];
    // ---- GEMM1 ----
#pragma unroll
    for (int i = 0; i < 4; ++i)
#pragma unroll
        for (int j = 0; j < 4; ++j) a[i][j] = 0.f;
#pragma unroll
    for (int k = 0; k < NF; ++k) {
        float4 xv = *(const float4*)&xs[k * 68 + r0];
        float4 wv = *(const float4*)&w1s[k * EMB + c0];
        float xa[4] = {xv.x, xv.y, xv.z, xv.w};
        float wa[4] = {wv.x, wv.y, wv.z, wv.w};
#pragma unroll
        for (int i = 0; i < 4; ++i)
#pragma unroll
            for (int j = 0; j < 4; ++j)
                a[i][j] = fmaf(xa[i], wa[j], a[i][j]);
    }
    __syncthreads();                    // un (xs,w1s) reads complete
    {
        float ba[4] = {b1v.x, b1v.y, b1v.z, b1v.w};
#pragma unroll
        for (int j = 0; j < 4; ++j) {
            float4 o;
            o.x = fmaxf(a[0][j] + ba[j], 0.f);
            o.y = fmaxf(a[1][j] + ba[j], 0.f);
            o.z = fmaxf(a[2][j] + ba[j], 0.f);
            o.w = fmaxf(a[3][j] + ba[j], 0.f);
            *(float4*)&hs[(c0 + j) * 68 + r0] = o;
        }
    }
    {
        const float4* wg = (const float4*)w2;
        float4* wl = (float4*)un;
#pragma unroll
        for (int q = 0; q < 4; ++q) wl[t + q * 256] = wg[t + q * 256];
    }
    __syncthreads();

    // ---- GEMM2 ----
#pragma unroll
    for (int i = 0; i < 4; ++i)
#pragma unroll
        for (int j = 0; j < 4; ++j) a[i][j] = 0.f;
#pragma unroll 8
    for (int k = 0; k < EMB; ++k) {
        float4 xv = *(const float4*)&hs[k * 68 + r0];
        float4 wv = *(const float4*)&un[k * EMB + c0];
        float xa[4] = {xv.x, xv.y, xv.z, xv.w};
        float wa[4] = {wv.x, wv.y, wv.z, wv.w};
#pragma unroll
        for (int i = 0; i < 4; ++i)
#pragma unroll
            for (int j = 0; j < 4; ++j)
                a[i][j] = fmaf(xa[i], wa[j], a[i][j]);
    }
    __syncthreads();                    // hs (h) + un (w2) reads complete
    {
        float ba[4] = {b2v.x, b2v.y, b2v.z, b2v.w};
#pragma unroll
        for (int j = 0; j < 4; ++j) {
            float4 o;
            o.x = fmaxf(a[0][j] + ba[j], 0.f);
            o.y = fmaxf(a[1][j] + ba[j], 0.f);
            o.z = fmaxf(a[2][j] + ba[j], 0.f);
            o.w = fmaxf(a[3][j] + ba[j], 0.f);
            *(float4*)&hs[(c0 + j) * 68 + r0] = o;
        }
    }
    {
        const float4* wg = (const float4*)wll;
        float4* wl = (float4*)un;
#pragma unroll
        for (int q = 0; q < 4; ++q) wl[t + q * 256] = wg[t + q * 256];
    }
    __syncthreads();

    // ---- GEMM3: tb = bf16(xhat @ Wll) ----
#pragma unroll
    for (int i = 0; i < 4; ++i)
#pragma unroll
        for (int j = 0; j < 4; ++j) a[i][j] = 0.f;
#pragma unroll 8
    for (int k = 0; k < EMB; ++k) {
        float4 xv = *(const float4*)&hs[k * 68 + r0];
        float4 wv = *(const float4*)&un[k * EMB + c0];
        float xa[4] = {xv.x, xv.y, xv.z, xv.w};
        float wa[4] = {wv.x, wv.y, wv.z, wv.w};
#pragma unroll
        for (int i = 0; i < 4; ++i)
#pragma unroll
            for (int j = 0; j < 4; ++j)
                a[i][j] = fmaf(xa[i], wa[j], a[i][j]);
    }
    __syncthreads();                    // un (wll) reads complete
    {
        const float4* wg = (const float4*)wlr;
        float4* wl = (float4*)un;
#pragma unroll
        for (int q = 0; q < 4; ++q) wl[t + q * 256] = wg[t + q * 256];
    }
#pragma unroll
    for (int i = 0; i < 4; ++i) {
        long gr = row0 + r0 + i;
        if (gr < n) {
            ushort4 o;
            o.x = f2bf(a[i][0]); o.y = f2bf(a[i][1]);
            o.z = f2bf(a[i][2]); o.w = f2bf(a[i][3]);
            *(ushort4*)(tb + gr * EMB + c0) = o;
        }
    }
    __syncthreads();

    // ---- GEMM4: u = xhat @ Wlr ----
#pragma unroll
    for (int i = 0; i < 4; ++i)
#pragma unroll
        for (int j = 0; j < 4; ++j) a[i][j] = 0.f;
#pragma unroll 8
    for (int k = 0; k < EMB; ++k) {
        float4 xv = *(const float4*)&hs[k * 68 + r0];
        float4 wv = *(const float4*)&un[k * EMB + c0];
        float xa[4] = {xv.x, xv.y, xv.z, xv.w};
        float wa[4] = {wv.x, wv.y, wv.z, wv.w};
#pragma unroll
        for (int i = 0; i < 4; ++i)
#pragma unroll
            for (int j = 0; j < 4; ++j)
                a[i][j] = fmaf(xa[i], wa[j], a[i][j]);
    }
#pragma unroll
    for (int i = 0; i < 4; ++i) {
        long gr = row0 + r0 + i;
        if (gr < n)
            *(float4*)&u[gr * EMB + c0] = make_float4(a[i][0], a[i][1], a[i][2], a[i][3]);
    }
}

template <int NFA, int NFB>
__global__ __launch_bounds__(256) void embed_dual_kernel(
    const float* xA, const float* shA, const float* scA,
    const float* w1A, const float* b1A, const float* w2A, const float* b2A,
    const float* wllA, const float* wlrA, unsigned short* tbA, float* uA, int nA,
    const float* xB, const float* shB, const float* scB,
    const float* w1B, const float* b1B, const float* w2B, const float* b2B,
    const float* wllB, const float* wlrB, unsigned short* tbB, float* uB, int nB,
    int split)
{
    __shared__ __align__(16) float hs[EMB * 68];
    __shared__ __align__(16) float un[4096];
    if ((int)blockIdx.x < split)
        embed_body<NFA>(hs, un, xA, shA, scA, w1A, b1A, w2A, b2A, wllA, wlrA, tbA, uA, nA, blockIdx.x);
    else
        embed_body<NFB>(hs, un, xB, shB, scB, w1B, b1B, w2B, b2B, wllB, wlrB, tbB, uB, nB, blockIdx.x - split);
}

// Layer-1 GEMMs, both sides in one dispatch (A: bf16 out, B: f32 out).
__global__ __launch_bounds__(256) void gemm64_dual_kernel(
    const float* __restrict__ XA, int nA, const float* __restrict__ WA, unsigned short* __restrict__ CA,
    const float* __restrict__ XB, int nB, const float* __restrict__ WB, float* __restrict__ CB, int split)
{
    __shared__ __align__(16) float xs[EMB * 68];
    __shared__ __align__(16) float w1s[EMB * EMB];

    const float* X; const float* W; int n; int bid; bool bf;
    if ((int)blockIdx.x < split) { X = XA; W = WA; n = nA; bid = blockIdx.x; bf = true; }
    else { X = XB; W = WB; n = nB; bid = blockIdx.x - split; bf = false; }

    int t = threadIdx.x;
    {
        int r = t >> 2;
        int cs = (t & 3) * 16;
        long gr = (long)bid * 64 + r;
        float4 v[4];
        if (gr < n) {
            const float4* sp = (const float4*)(X + gr * EMB + cs);
#pragma unroll
            for (int q = 0; q < 4; ++q) v[q] = sp[q];
        } else {
            float4 z = make_float4(0.f, 0.f, 0.f, 0.f);
#pragma unroll
            for (int q = 0; q < 4; ++q) v[q] = z;
        }
#pragma unroll
        for (int q = 0; q < 4; ++q) {
            xs[(cs + q * 4 + 0) * 68 + r] = v[q].x;
            xs[(cs + q * 4 + 1) * 68 + r] = v[q].y;
            xs[(cs + q * 4 + 2) * 68 + r] = v[q].z;
            xs[(cs + q * 4 + 3) * 68 + r] = v[q].w;
        }
        const float4* wg = (const float4*)W;
        float4* wl = (float4*)w1s;
#pragma unroll
        for (int q = 0; q < 4; ++q) wl[t + q * 256] = wg[t + q * 256];
    }
    __syncthreads();

    int r0 = (t >> 4) * 4;
    int c0 = (t & 15) * 4;
    float acc[4][4] = {{0.f}};
#pragma unroll 8
    for (int k = 0; k < EMB; ++k) {
        float4 xv = *(const float4*)&xs[k * 68 + r0];
        float4 wv = *(const float4*)&w1s[k * EMB + c0];
        float xa[4] = {xv.x, xv.y, xv.z, xv.w};
        float wa[4] = {wv.x, wv.y, wv.z, wv.w};
#pragma unroll
        for (int i = 0; i < 4; ++i)
#pragma unroll
            for (int j = 0; j < 4; ++j)
                acc[i][j] = fmaf(xa[i], wa[j], acc[i][j]);
    }

#pragma unroll
    for (int i = 0; i < 4; ++i) {
        long gr = (long)bid * 64 + r0 + i;
        if (gr < n) {
            if (bf) {
                ushort4 o;
                o.x = f2bf(acc[i][0]); o.y = f2bf(acc[i][1]);
                o.z = f2bf(acc[i][2]); o.w = f2bf(acc[i][3]);
                *(ushort4*)(CA + gr * EMB + c0) = o;
            } else {
                *(float4*)(CB + gr * EMB + c0) =
                    make_float4(acc[i][0], acc[i][1], acc[i][2], acc[i][3]);
            }
        }
    }
}

// out[node] = relu(mean_nbr tb[nbr] + bias + out[node])  (RMW; out holds u)
// 4 nodes/block, 1 node/wave. lane = 8*g + p: slot g in [0,8), oct p in
// [0,8); lane loads uint4 = 16B = 8 bf16. One wave load = 8 rows = 1KB.
__global__ __launch_bounds__(256) void agg_rmw_kernel(
    const unsigned short* __restrict__ tbl, const int* __restrict__ rowptr,
    const int* __restrict__ adj, const float* __restrict__ bias,
    float* __restrict__ out, int n_dst)
{
    int lane = threadIdx.x & 63;
    int node = blockIdx.x * 4 + (threadIdx.x >> 6);
    if (node >= n_dst) return;
    int p = lane & 7;      // feature oct: bf16 [8p, 8p+8)
    int g = lane >> 3;     // neighbor slot 0..7
    int beg = rowptr[node];
    int end = rowptr[node + 1];
    const uint4* tb = (const uint4*)tbl;   // row stride = 8 uint4 (128B)
    float a0 = 0.f, a1 = 0.f, a2 = 0.f, a3 = 0.f;
    float a4 = 0.f, a5 = 0.f, a6 = 0.f, a7 = 0.f;
    int e = beg + g;
    for (; e + 8 < end; e += 16) {
        int r0 = adj[e];
        int r1 = adj[e + 8];
        uint4 w0 = tb[(long)r0 * 8 + p];
        uint4 w1 = tb[(long)r1 * 8 + p];
        a0 += bflo(w0.x) + bflo(w1.x);
        a1 += bfhi(w0.x) + bfhi(w1.x);
        a2 += bflo(w0.y) + bflo(w1.y);
        a3 += bfhi(w0.y) + bfhi(w1.y);
        a4 += bflo(w0.z) + bflo(w1.z);
        a5 += bfhi(w0.z) + bfhi(w1.z);
        a6 += bflo(w0.w) + bflo(w1.w);
        a7 += bfhi(w0.w) + bfhi(w1.w);
    }
    if (e < end) {
        uint4 w0 = tb[(long)adj[e] * 8 + p];
        a0 += bflo(w0.x); a1 += bfhi(w0.x);
        a2 += bflo(w0.y); a3 += bfhi(w0.y);
        a4 += bflo(w0.z); a5 += bfhi(w0.z);
        a6 += bflo(w0.w); a7 += bfhi(w0.w);
    }
    a0 += __shfl_xor(a0, 8); a0 += __shfl_xor(a0, 16); a0 += __shfl_xor(a0, 32);
    a1 += __shfl_xor(a1, 8); a1 += __shfl_xor(a1, 16); a1 += __shfl_xor(a1, 32);
    a2 += __shfl_xor(a2, 8); a2 += __shfl_xor(a2, 16); a2 += __shfl_xor(a2, 32);
    a3 += __shfl_xor(a3, 8); a3 += __shfl_xor(a3, 16); a3 += __shfl_xor(a3, 32);
    a4 += __shfl_xor(a4, 8); a4 += __shfl_xor(a4, 16); a4 += __shfl_xor(a4, 32);
    a5 += __shfl_xor(a5, 8); a5 += __shfl_xor(a5, 16); a5 += __shfl_xor(a5, 32);
    a6 += __shfl_xor(a6, 8); a6 += __shfl_xor(a6, 16); a6 += __shfl_xor(a6, 32);
    a7 += __shfl_xor(a7, 8); a7 += __shfl_xor(a7, 16); a7 += __shfl_xor(a7, 32);
    if (g == 0) {
        int cnt = end - beg;
        float inv = 1.f / (float)(cnt > 0 ? cnt : 1);
        const float4* bp = (const float4*)bias + 2 * p;
        float4 bv0 = bp[0], bv1 = bp[1];
        float4* op = (float4*)(out + (long)node * EMB) + 2 * p;
        float4 ov0 = op[0], ov1 = op[1];
        float4 o0, o1;
        o0.x = fmaxf(a0 * inv + bv0.x + ov0.x, 0.f);
        o0.y = fmaxf(a1 * inv + bv0.y + ov0.y, 0.f);
        o0.z = fmaxf(a2 * inv + bv0.z + ov0.z, 0.f);
        o0.w = fmaxf(a3 * inv + bv0.w + ov0.w, 0.f);
        o1.x = fmaxf(a4 * inv + bv1.x + ov1.x, 0.f);
        o1.y = fmaxf(a5 * inv + bv1.y + ov1.y, 0.f);
        o1.z = fmaxf(a6 * inv + bv1.z + ov1.z, 0.f);
        o1.w = fmaxf(a7 * inv + bv1.w + ov1.w, 0.f);
        op[0] = o0;
        op[1] = o1;
    }
}

extern "C" void kernel_launch(void* const* d_in, const int* in_sizes, int n_in,
                              void* d_out, int out_size, void* d_ws, size_t ws_size,
                              hipStream_t stream) {
    const float* cons_x     = (const float*)d_in[0];
    const float* var_x      = (const float*)d_in[1];
    const int*   eidx       = (const int*)d_in[3];
    const float* cons_shift = (const float*)d_in[4];
    const float* cons_scale = (const float*)d_in[5];
    const float* cons_w1    = (const float*)d_in[6];
    const float* cons_b1    = (const float*)d_in[7];
    const float* cons_w2    = (const float*)d_in[8];
    const float* cons_b2    = (const float*)d_in[9];
    const float* var_shift  = (const float*)d_in[10];
    const float* var_scale  = (const float*)d_in[11];
    const float* var_w1     = (const float*)d_in[12];
    const float* var_b1     = (const float*)d_in[13];
    const float* var_w2     = (const float*)d_in[14];
    const float* var_b2     = (const float*)d_in[15];
    const float* ll_w       = (const float*)d_in[18];
    const float* ll_b       = (const float*)d_in[19];
    const float* lr_w       = (const float*)d_in[20];

    const int nC = in_sizes[0] / 5;
    const int nV = in_sizes[1] / 19;
    const int E  = in_sizes[3] / 2;
    const int* src = eidx;       // constraint ids
    const int* dst = eidx + E;   // variable ids

    int shc = 0; while ((nC >> shc) >= 512) ++shc;
    int shv = 0; while ((nV >> shv) >= 512) ++shv;
    const int NBC = (nC + (1 << shc) - 1) >> shc;
    const int NBV = (nV + (1 << shv) - 1) >> shv;

    char* w = (char*)d_ws;
    auto alloc = [&](size_t bytes) {
        char* p = w;
        w += (bytes + 255) & ~(size_t)255;
        return p;
    };
    float* x_c = (float*)alloc((size_t)nC * EMB * 4);   // u_c, then xhat_c
    float* x_v = (float*)alloc((size_t)nV * EMB * 4);   // u_v, then xhat_v
    float* t_c = (float*)alloc((size_t)nC * EMB * 4);   // aliases: slotted tmp_c, then bf16 tb_c
    float* t_v = (float*)alloc((size_t)nV * EMB * 4);
    unsigned* tmp_c = (unsigned*)t_c;
    unsigned* tmp_v = (unsigned*)t_v;
    unsigned short* tb_c = (unsigned short*)t_c;
    unsigned short* tb_v = (unsigned short*)t_v;
    int* rp_v  = (int*)alloc((size_t)(nV + 1) * 4);
    int* rp_c  = (int*)alloc((size_t)(nC + 1) * 4);
    int* adj_v = (int*)alloc((size_t)E * 4);
    int* adj_c = (int*)alloc((size_t)E * 4);
    int* bkt   = (int*)alloc(2048 * 4);
    int* gcur_c = bkt;            // counts, then exclusive bases (NBC+1)
    int* gcur_v = bkt + 1024;     // counts, then exclusive bases (NBV+1)

    // fixed per-bucket slots in tmp (2x mean, clamped to region capacity)
    auto slot_for = [&](int NB, size_t cap_ints) {
        long s = 2L * E / NB;
        s = (s + 255) & ~255L;
        if (s < 4096) s = 4096;
        long cap = (long)(cap_ints / NB) & ~255L;
        if (s > cap) s = cap;
        return (int)s;
    };
    const int SLOTC = slot_for(NBC, (size_t)nC * EMB);
    const int SLOTV = slot_for(NBV, (size_t)nV * EMB);

    auto llw = [&](int l, int d) { return ll_w + (size_t)(l * 2 + d) * EMB * EMB; };
    auto lrw = [&](int l, int d) { return lr_w + (size_t)(l * 2 + d) * EMB * EMB; };
    auto llb = [&](int l, int d) { return ll_b + (size_t)(l * 2 + d) * EMB; };

    // ---- CSR build (no histogram pass: fixed slots + post-scan) ----
    zero_int_kernel<<<8, 256, 0, stream>>>(bkt, 2048);
    bin_edges_kernel<<<(E + CH - 1) / CH, 256, 0, stream>>>(src, dst, E, gcur_c, gcur_v,
                                                            tmp_c, tmp_v, shc, shv, NBC, NBV,
                                                            SLOTC, SLOTV);
    scan_buckets_kernel<<<1, 256, 0, stream>>>(gcur_c, NBC, gcur_v, NBV, E);
    regroup2_dual_kernel<<<NBV + NBC, 256, 0, stream>>>(
        tmp_v, gcur_v, rp_v, adj_v, nV, shv, NBV, SLOTV,
        tmp_c, gcur_c, rp_c, adj_c, nC, shc, NBC, SLOTC, E);

    // ---- fused embed + layer-0 GEMMs, both sides in one dispatch ----
    int gc = (nC + 63) / 64, gv = (nV + 63) / 64;
    embed_dual_kernel<5, 19><<<gc + gv, 256, 0, stream>>>(
        cons_x, cons_shift, cons_scale, cons_w1, cons_b1, cons_w2, cons_b2,
        llw(0, 0), lrw(0, 1), tb_c, x_c, nC,
        var_x, var_shift, var_scale, var_w1, var_b1, var_w2, var_b2,
        llw(0, 1), lrw(0, 0), tb_v, x_v, nV,
        gc);

    // ---- layer-0 aggs (RMW u -> xhat), SEQUENTIAL (L2 working-set) ----
    int gv4 = (nV + 3) / 4, gc4 = (nC + 3) / 4;
    agg_rmw_kernel<<<gv4, 256, 0, stream>>>(tb_c, rp_v, adj_v, llb(0, 0), x_v, nV);
    agg_rmw_kernel<<<gc4, 256, 0, stream>>>(tb_v, rp_c, adj_c, llb(0, 1), x_c, nC);

    // ---- layer-1 GEMMs, one dispatch ----
    gemm64_dual_kernel<<<gc + gv, 256, 0, stream>>>(
        x_c, nC, llw(1, 0), tb_c,
        x_v, nV, lrw(1, 0), (float*)d_out, gc);

    // ---- final layer-1 var agg (RMW d_out) ----
    agg_rmw_kernel<<<gv4, 256, 0, stream>>>(tb_c, rp_v, adj_v, llb(1, 0), (float*)d_out, nV);
}

// Round 14
// 388.371 us; speedup vs baseline: 1.3269x; 1.1312x over previous
//
#include <hip/hip_runtime.h>

#define EMB 64
#define CH 4096

// ---------------------------------------------------------------------------
// Round 14:
//  - embed: hs tile -> XOR-swizzled float4[1024] (exactly 16KB; slot =
//    c*16 + (rb ^ (c&15))). Total LDS = 32KB -> 5 blocks/CU (was 33.8KB/4).
//    Stores hit all 8 b128 bank-start positions (balanced); reads are
//    permuted broadcasts. Bit-identical arithmetic.
//  - agg: quarter-wave per node (lane = slot g in [0,2) x oct p in [0,8)),
//    4 nodes/wave, 16 nodes/block; reduce = ONE shfl_xor(8) per acc
//    (was 3 levels). Same 8-rows-per-load width. Mean degree 10-20 makes
//    per-node overhead matter.
//  - rest unchanged from r13 (slotted CSR, sequential aggs, dual gemm).
// ---------------------------------------------------------------------------

static __device__ __forceinline__ unsigned short f2bf(float x) {
    union { float f; unsigned u; } v; v.f = x;
    unsigned r = v.u + 0x7fffu + ((v.u >> 16) & 1u);   // RNE
    return (unsigned short)(r >> 16);
}
static __device__ __forceinline__ float bflo(unsigned w) {
    union { unsigned u; float f; } v; v.u = w << 16; return v.f;
}
static __device__ __forceinline__ float bfhi(unsigned w) {
    union { unsigned u; float f; } v; v.u = w & 0xffff0000u; return v.f;
}

__global__ __launch_bounds__(256) void zero_int_kernel(int* __restrict__ p, int n) {
    int i = blockIdx.x * 256 + threadIdx.x;
    if (i < n) p[i] = 0;
}

// one block: exclusive-scan both count arrays in place (n<=512 each); data[n]=E
__global__ __launch_bounds__(256) void scan_buckets_kernel(
    int* __restrict__ bc, int nbc, int* __restrict__ bv, int nbv, int E)
{
    __shared__ int sc[256];
    int t = threadIdx.x;
    {
        int v0 = (2 * t < nbc) ? bc[2 * t] : 0;
        int v1 = (2 * t + 1 < nbc) ? bc[2 * t + 1] : 0;
        sc[t] = v0 + v1;
        __syncthreads();
        for (int off = 1; off < 256; off <<= 1) {
            int x = (t >= off) ? sc[t - off] : 0;
            __syncthreads();
            sc[t] += x;
            __syncthreads();
        }
        int ex = (t > 0) ? sc[t - 1] : 0;
        if (2 * t < nbc) bc[2 * t] = ex;
        if (2 * t + 1 < nbc) bc[2 * t + 1] = ex + v0;
        if (t == 0) bc[nbc] = E;
        __syncthreads();
    }
    {
        int v0 = (2 * t < nbv) ? bv[2 * t] : 0;
        int v1 = (2 * t + 1 < nbv) ? bv[2 * t + 1] : 0;
        sc[t] = v0 + v1;
        __syncthreads();
        for (int off = 1; off < 256; off <<= 1) {
            int x = (t >= off) ? sc[t - off] : 0;
            __syncthreads();
            sc[t] += x;
            __syncthreads();
        }
        int ex = (t > 0) ? sc[t - 1] : 0;
        if (2 * t < nbv) bv[2 * t] = ex;
        if (2 * t + 1 < nbv) bv[2 * t + 1] = ex + v0;
        if (t == 0) bv[nbv] = E;
    }
}

// Phase 1: per-chunk LDS binning into FIXED per-bucket slots (base=i*SLOT),
// global per-bucket cursors count occupancy. Packed u32 {local<<23 | other}.
__global__ __launch_bounds__(256) void bin_edges_kernel(
    const int* __restrict__ src, const int* __restrict__ dst, int E,
    int* __restrict__ gcur_c, int* __restrict__ gcur_v,
    unsigned* __restrict__ tmp_c, unsigned* __restrict__ tmp_v,
    int shc, int shv, int NBC, int NBV, int SLOTC, int SLOTV)
{
    __shared__ int hc[512], hv[512];
    int t = threadIdx.x;
    int base = blockIdx.x * CH;
    int n = min(CH, E - base);
    unsigned mc = (1u << shc) - 1u, mv = (1u << shv) - 1u;

    for (int i = t; i < NBC; i += 256) hc[i] = 0;
    for (int i = t; i < NBV; i += 256) hv[i] = 0;
    __syncthreads();

    int ss[16], dd[16];
#pragma unroll
    for (int q = 0; q < 16; ++q) {
        int li = t + q * 256;
        bool ok = li < n;
        ss[q] = ok ? src[base + li] : -1;
        dd[q] = ok ? dst[base + li] : -1;
        if (ok) {
            atomicAdd(&hc[ss[q] >> shc], 1);
            atomicAdd(&hv[dd[q] >> shv], 1);
        }
    }
    __syncthreads();

    for (int i = t; i < NBC; i += 256) {
        int c = hc[i];
        hc[i] = c ? (i * SLOTC + atomicAdd(&gcur_c[i], c)) : 0;
    }
    for (int i = t; i < NBV; i += 256) {
        int c = hv[i];
        hv[i] = c ? (i * SLOTV + atomicAdd(&gcur_v[i], c)) : 0;
    }
    __syncthreads();

#pragma unroll
    for (int q = 0; q < 16; ++q) {
        int li = t + q * 256;
        if (li < n) {
            unsigned s = (unsigned)ss[q], d = (unsigned)dd[q];
            int pc = atomicAdd(&hc[s >> shc], 1);
            tmp_c[pc] = ((s & mc) << 23) | d;
            int pv = atomicAdd(&hv[d >> shv], 1);
            tmp_v[pv] = ((d & mv) << 23) | s;
        }
    }
}

// Phase 2 (dual): wg-per-bucket; reads slotted tmp, writes packed rp/adj.
__global__ __launch_bounds__(256) void regroup2_dual_kernel(
    const unsigned* __restrict__ tmpA, const int* __restrict__ bbA,
    int* __restrict__ rpA, int* __restrict__ adjA, int nAn, int shA, int nbA, int slotA,
    const unsigned* __restrict__ tmpB, const int* __restrict__ bbB,
    int* __restrict__ rpB, int* __restrict__ adjB, int nBn, int shB, int nbB, int slotB, int E)
{
    __shared__ int cnt[512];
    __shared__ int offs[512];
    __shared__ int sc[256];
    const unsigned* tmp; const int* bb; int* rp; int* adj; int n_nodes, sh, nb, b, slot;
    if ((int)blockIdx.x < nbA) {
        tmp = tmpA; bb = bbA; rp = rpA; adj = adjA; n_nodes = nAn; sh = shA; nb = nbA; slot = slotA; b = blockIdx.x;
    } else {
        tmp = tmpB; bb = bbB; rp = rpB; adj = adjB; n_nodes = nBn; sh = shB; nb = nbB; slot = slotB; b = blockIdx.x - nbA;
    }
    int t = threadIdx.x;
    int node0 = b << sh;
    int node1 = min(node0 + (1 << sh), n_nodes);
    int nn = node1 - node0;
    for (int i = t; i < nn; i += 256) cnt[i] = 0;
    __syncthreads();
    int adjbase = bb[b];
    int cntb = bb[b + 1] - adjbase;
    int sbeg = b * slot;
    for (int e = sbeg + t; e < sbeg + cntb; e += 256)
        atomicAdd(&cnt[tmp[e] >> 23], 1);
    __syncthreads();
    int v0 = (2 * t < nn) ? cnt[2 * t] : 0;
    int v1 = (2 * t + 1 < nn) ? cnt[2 * t + 1] : 0;
    sc[t] = v0 + v1;
    __syncthreads();
    for (int off = 1; off < 256; off <<= 1) {
        int x = (t >= off) ? sc[t - off] : 0;
        __syncthreads();
        sc[t] += x;
        __syncthreads();
    }
    int ex = (t > 0) ? sc[t - 1] : 0;
    if (2 * t < nn) offs[2 * t] = ex;
    if (2 * t + 1 < nn) offs[2 * t + 1] = ex + v0;
    __syncthreads();
    for (int i = t; i < nn; i += 256) {
        rp[node0 + i] = adjbase + offs[i];
        cnt[i] = 0;
    }
    if (b == nb - 1 && t == 0) rp[n_nodes] = E;
    __syncthreads();
    for (int e = sbeg + t; e < sbeg + cntb; e += 256) {
        unsigned p = tmp[e];
        int d = (int)(p >> 23);
        int r = atomicAdd(&cnt[d], 1);
        adj[adjbase + offs[d] + r] = (int)(p & 0x7fffffu);
    }
}

// ---------------------------------------------------------------------------
// Fused node pipeline body (EXACTLY 32KB LDS: hsf float4[1024] + un[4096]).
// hs tile XOR-swizzled: column c, row-block rb (4 rows) lives at
// hsf[c*16 + (rb ^ (c & 15))]. Stores: 8 balanced b128 bank-starts.
// Reads (fixed c, rb = t>>4): permutation of 16 slots, broadcast x4 lanes.
// ---------------------------------------------------------------------------
template <int NF>
__device__ __forceinline__ void embed_body(
    float4* hsf, float* un,
    const float* __restrict__ x, const float* __restrict__ shift, const float* __restrict__ scale,
    const float* __restrict__ w1, const float* __restrict__ b1,
    const float* __restrict__ w2, const float* __restrict__ b2,
    const float* __restrict__ wll, const float* __restrict__ wlr,
    unsigned short* __restrict__ tb, float* __restrict__ u, int n, int bid)
{
    int t = threadIdx.x;
    long row0 = (long)bid * 64;
    int nrow = (n - row0 < 64) ? (int)(n - row0) : 64;

    float* xs  = un;             // [NF][68] (transposed, prenormed)
    float* w1s = un + NF * 68;   // [NF][64]

    for (int i = t; i < NF * EMB; i += 256) w1s[i] = w1[i];
    for (int i = t; i < 64 * NF; i += 256) {
        int r = i / NF, k = i - r * NF;
        float v = (r < nrow) ? x[row0 * NF + i] : 0.f;
        xs[k * 68 + r] = (v + shift[k]) * scale[k];
    }
    int rb = t >> 4;             // row-block (4 rows)
    int r0 = rb * 4;
    int c0 = (t & 15) * 4;
    float4 b1v = *(const float4*)&b1[c0];
    float4 b2v = *(const float4*)&b2[c0];
    __syncthreads();

    float a[4][4];
    // ---- GEMM1: h = relu(xs @ W1 + b1) ----
#pragma unroll
    for (int i = 0; i < 4; ++i)
#pragma unroll
        for (int j = 0; j < 4; ++j) a[i][j] = 0.f;
#pragma unroll
    for (int k = 0; k < NF; ++k) {
        float4 xv = *(const float4*)&xs[k * 68 + r0];
        float4 wv = *(const float4*)&w1s[k * EMB + c0];
        float xa[4] = {xv.x, xv.y, xv.z, xv.w};
        float wa[4] = {wv.x, wv.y, wv.z, wv.w};
#pragma unroll
        for (int i = 0; i < 4; ++i)
#pragma unroll
            for (int j = 0; j < 4; ++j)
                a[i][j] = fmaf(xa[i], wa[j], a[i][j]);
    }
    __syncthreads();                    // un (xs,w1s) reads complete
    {
        float ba[4] = {b1v.x, b1v.y, b1v.z, b1v.w};
#pragma unroll
        for (int j = 0; j < 4; ++j) {
            int c = c0 + j;
            float4 o;
            o.x = fmaxf(a[0][j] + ba[j], 0.f);
            o.y = fmaxf(a[1][j] + ba[j], 0.f);
            o.z = fmaxf(a[2][j] + ba[j], 0.f);
            o.w = fmaxf(a[3][j] + ba[j], 0.f);
            hsf[c * 16 + (rb ^ (c & 15))] = o;
        }
    }
    {
        const float4* wg = (const float4*)w2;
        float4* wl = (float4*)un;
#pragma unroll
        for (int q = 0; q < 4; ++q) wl[t + q * 256] = wg[t + q * 256];
    }
    __syncthreads();

    // ---- GEMM2: xhat = relu(h @ W2 + b2) ----
#pragma unroll
    for (int i = 0; i < 4; ++i)
#pragma unroll
        for (int j = 0; j < 4; ++j) a[i][j] = 0.f;
#pragma unroll 8
    for (int k = 0; k < EMB; ++k) {
        float4 xv = hsf[k * 16 + (rb ^ (k & 15))];
        float4 wv = *(const float4*)&un[k * EMB + c0];
        float xa[4] = {xv.x, xv.y, xv.z, xv.w};
        float wa[4] = {wv.x, wv.y, wv.z, wv.w};
#pragma unroll
        for (int i = 0; i < 4; ++i)
#pragma unroll
            for (int j = 0; j < 4; ++j)
                a[i][j] = fmaf(xa[i], wa[j], a[i][j]);
    }
    __syncthreads();                    // hsf (h) + un (w2) reads complete
    {
        float ba[4] = {b2v.x, b2v.y, b2v.z, b2v.w};
#pragma unroll
        for (int j = 0; j < 4; ++j) {
            int c = c0 + j;
            float4 o;
            o.x = fmaxf(a[0][j] + ba[j], 0.f);
            o.y = fmaxf(a[1][j] + ba[j], 0.f);
            o.z = fmaxf(a[2][j] + ba[j], 0.f);
            o.w = fmaxf(a[3][j] + ba[j], 0.f);
            hsf[c * 16 + (rb ^ (c & 15))] = o;
        }
    }
    {
        const float4* wg = (const float4*)wll;
        float4* wl = (float4*)un;
#pragma unroll
        for (int q = 0; q < 4; ++q) wl[t + q * 256] = wg[t + q * 256];
    }
    __syncthreads();

    // ---- GEMM3: tb = bf16(xhat @ Wll) ----
#pragma unroll
    for (int i = 0; i < 4; ++i)
#pragma unroll
        for (int j = 0; j < 4; ++j) a[i][j] = 0.f;
#pragma unroll 8
    for (int k = 0; k < EMB; ++k) {
        float4 xv = hsf[k * 16 + (rb ^ (k & 15))];
        float4 wv = *(const float4*)&un[k * EMB + c0];
        float xa[4] = {xv.x, xv.y, xv.z, xv.w};
        float wa[4] = {wv.x, wv.y, wv.z, wv.w};
#pragma unroll
        for (int i = 0; i < 4; ++i)
#pragma unroll
            for (int j = 0; j < 4; ++j)
                a[i][j] = fmaf(xa[i], wa[j], a[i][j]);
    }
    __syncthreads();                    // un (wll) reads complete
    {
        const float4* wg = (const float4*)wlr;
        float4* wl = (float4*)un;
#pragma unroll
        for (int q = 0; q < 4; ++q) wl[t + q * 256] = wg[t + q * 256];
    }
#pragma unroll
    for (int i = 0; i < 4; ++i) {
        long gr = row0 + r0 + i;
        if (gr < n) {
            ushort4 o;
            o.x = f2bf(a[i][0]); o.y = f2bf(a[i][1]);
            o.z = f2bf(a[i][2]); o.w = f2bf(a[i][3]);
            *(ushort4*)(tb + gr * EMB + c0) = o;
        }
    }
    __syncthreads();

    // ---- GEMM4: u = xhat @ Wlr ----
#pragma unroll
    for (int i = 0; i < 4; ++i)
#pragma unroll
        for (int j = 0; j < 4; ++j) a[i][j] = 0.f;
#pragma unroll 8
    for (int k = 0; k < EMB; ++k) {
        float4 xv = hsf[k * 16 + (rb ^ (k & 15))];
        float4 wv = *(const float4*)&un[k * EMB + c0];
        float xa[4] = {xv.x, xv.y, xv.z, xv.w};
        float wa[4] = {wv.x, wv.y, wv.z, wv.w};
#pragma unroll
        for (int i = 0; i < 4; ++i)
#pragma unroll
            for (int j = 0; j < 4; ++j)
                a[i][j] = fmaf(xa[i], wa[j], a[i][j]);
    }
#pragma unroll
    for (int i = 0; i < 4; ++i) {
        long gr = row0 + r0 + i;
        if (gr < n)
            *(float4*)&u[gr * EMB + c0] = make_float4(a[i][0], a[i][1], a[i][2], a[i][3]);
    }
}

template <int NFA, int NFB>
__global__ __launch_bounds__(256) void embed_dual_kernel(
    const float* xA, const float* shA, const float* scA,
    const float* w1A, const float* b1A, const float* w2A, const float* b2A,
    const float* wllA, const float* wlrA, unsigned short* tbA, float* uA, int nA,
    const float* xB, const float* shB, const float* scB,
    const float* w1B, const float* b1B, const float* w2B, const float* b2B,
    const float* wllB, const float* wlrB, unsigned short* tbB, float* uB, int nB,
    int split)
{
    __shared__ float4 hsf[1024];                 // 16KB, XOR-swizzled
    __shared__ __align__(16) float un[4096];     // 16KB
    if ((int)blockIdx.x < split)
        embed_body<NFA>(hsf, un, xA, shA, scA, w1A, b1A, w2A, b2A, wllA, wlrA, tbA, uA, nA, blockIdx.x);
    else
        embed_body<NFB>(hsf, un, xB, shB, scB, w1B, b1B, w2B, b2B, wllB, wlrB, tbB, uB, nB, blockIdx.x - split);
}

// Layer-1 GEMMs, both sides in one dispatch (A: bf16 out, B: f32 out).
__global__ __launch_bounds__(256) void gemm64_dual_kernel(
    const float* __restrict__ XA, int nA, const float* __restrict__ WA, unsigned short* __restrict__ CA,
    const float* __restrict__ XB, int nB, const float* __restrict__ WB, float* __restrict__ CB, int split)
{
    __shared__ __align__(16) float xs[EMB * 68];
    __shared__ __align__(16) float w1s[EMB * EMB];

    const float* X; const float* W; int n; int bid; bool bf;
    if ((int)blockIdx.x < split) { X = XA; W = WA; n = nA; bid = blockIdx.x; bf = true; }
    else { X = XB; W = WB; n = nB; bid = blockIdx.x - split; bf = false; }

    int t = threadIdx.x;
    {
        int r = t >> 2;
        int cs = (t & 3) * 16;
        long gr = (long)bid * 64 + r;
        float4 v[4];
        if (gr < n) {
            const float4* sp = (const float4*)(X + gr * EMB + cs);
#pragma unroll
            for (int q = 0; q < 4; ++q) v[q] = sp[q];
        } else {
            float4 z = make_float4(0.f, 0.f, 0.f, 0.f);
#pragma unroll
            for (int q = 0; q < 4; ++q) v[q] = z;
        }
#pragma unroll
        for (int q = 0; q < 4; ++q) {
            xs[(cs + q * 4 + 0) * 68 + r] = v[q].x;
            xs[(cs + q * 4 + 1) * 68 + r] = v[q].y;
            xs[(cs + q * 4 + 2) * 68 + r] = v[q].z;
            xs[(cs + q * 4 + 3) * 68 + r] = v[q].w;
        }
        const float4* wg = (const float4*)W;
        float4* wl = (float4*)w1s;
#pragma unroll
        for (int q = 0; q < 4; ++q) wl[t + q * 256] = wg[t + q * 256];
    }
    __syncthreads();

    int r0 = (t >> 4) * 4;
    int c0 = (t & 15) * 4;
    float acc[4][4] = {{0.f}};
#pragma unroll 8
    for (int k = 0; k < EMB; ++k) {
        float4 xv = *(const float4*)&xs[k * 68 + r0];
        float4 wv = *(const float4*)&w1s[k * EMB + c0];
        float xa[4] = {xv.x, xv.y, xv.z, xv.w};
        float wa[4] = {wv.x, wv.y, wv.z, wv.w};
#pragma unroll
        for (int i = 0; i < 4; ++i)
#pragma unroll
            for (int j = 0; j < 4; ++j)
                acc[i][j] = fmaf(xa[i], wa[j], acc[i][j]);
    }

#pragma unroll
    for (int i = 0; i < 4; ++i) {
        long gr = (long)bid * 64 + r0 + i;
        if (gr < n) {
            if (bf) {
                ushort4 o;
                o.x = f2bf(acc[i][0]); o.y = f2bf(acc[i][1]);
                o.z = f2bf(acc[i][2]); o.w = f2bf(acc[i][3]);
                *(ushort4*)(CA + gr * EMB + c0) = o;
            } else {
                *(float4*)(CB + gr * EMB + c0) =
                    make_float4(acc[i][0], acc[i][1], acc[i][2], acc[i][3]);
            }
        }
    }
}

// out[node] = relu(mean_nbr tb[nbr] + bias + out[node])  (RMW; out holds u)
// 16 nodes/block: quarter-wave (16 lanes) per node. lane = 8*g + p:
// slot g in [0,2), oct p in [0,8); lane loads uint4 = 16B = 8 bf16.
// One wave load instr = 8 rows (4 nodes x 2 slots) = 1KB.
// Reduce: ONE shfl_xor(8) per acc; g==0 lanes RMW 2x float4.
__global__ __launch_bounds__(256) void agg_rmw_kernel(
    const unsigned short* __restrict__ tbl, const int* __restrict__ rowptr,
    const int* __restrict__ adj, const float* __restrict__ bias,
    float* __restrict__ out, int n_dst)
{
    int t = threadIdx.x;
    int node = blockIdx.x * 16 + (t >> 4);
    if (node >= n_dst) return;
    int sub = t & 15;
    int p = sub & 7;       // feature oct: bf16 [8p, 8p+8)
    int g = sub >> 3;      // neighbor slot 0..1
    int beg = rowptr[node];
    int end = rowptr[node + 1];
    const uint4* tb = (const uint4*)tbl;   // row stride = 8 uint4 (128B)
    float a0 = 0.f, a1 = 0.f, a2 = 0.f, a3 = 0.f;
    float a4 = 0.f, a5 = 0.f, a6 = 0.f, a7 = 0.f;
    int e = beg + g;
    for (; e + 2 < end; e += 4) {
        int r0 = adj[e];
        int r1 = adj[e + 2];
        uint4 w0 = tb[(long)r0 * 8 + p];
        uint4 w1 = tb[(long)r1 * 8 + p];
        a0 += bflo(w0.x) + bflo(w1.x);
        a1 += bfhi(w0.x) + bfhi(w1.x);
        a2 += bflo(w0.y) + bflo(w1.y);
        a3 += bfhi(w0.y) + bfhi(w1.y);
        a4 += bflo(w0.z) + bflo(w1.z);
        a5 += bfhi(w0.z) + bfhi(w1.z);
        a6 += bflo(w0.w) + bflo(w1.w);
        a7 += bfhi(w0.w) + bfhi(w1.w);
    }
    if (e < end) {
        uint4 w0 = tb[(long)adj[e] * 8 + p];
        a0 += bflo(w0.x); a1 += bfhi(w0.x);
        a2 += bflo(w0.y); a3 += bfhi(w0.y);
        a4 += bflo(w0.z); a5 += bfhi(w0.z);
        a6 += bflo(w0.w); a7 += bfhi(w0.w);
    }
    a0 += __shfl_xor(a0, 8);
    a1 += __shfl_xor(a1, 8);
    a2 += __shfl_xor(a2, 8);
    a3 += __shfl_xor(a3, 8);
    a4 += __shfl_xor(a4, 8);
    a5 += __shfl_xor(a5, 8);
    a6 += __shfl_xor(a6, 8);
    a7 += __shfl_xor(a7, 8);
    if (g == 0) {
        int cnt = end - beg;
        float inv = 1.f / (float)(cnt > 0 ? cnt : 1);
        const float4* bp = (const float4*)bias + 2 * p;
        float4 bv0 = bp[0], bv1 = bp[1];
        float4* op = (float4*)(out + (long)node * EMB) + 2 * p;
        float4 ov0 = op[0], ov1 = op[1];
        float4 o0, o1;
        o0.x = fmaxf(a0 * inv + bv0.x + ov0.x, 0.f);
        o0.y = fmaxf(a1 * inv + bv0.y + ov0.y, 0.f);
        o0.z = fmaxf(a2 * inv + bv0.z + ov0.z, 0.f);
        o0.w = fmaxf(a3 * inv + bv0.w + ov0.w, 0.f);
        o1.x = fmaxf(a4 * inv + bv1.x + ov1.x, 0.f);
        o1.y = fmaxf(a5 * inv + bv1.y + ov1.y, 0.f);
        o1.z = fmaxf(a6 * inv + bv1.z + ov1.z, 0.f);
        o1.w = fmaxf(a7 * inv + bv1.w + ov1.w, 0.f);
        op[0] = o0;
        op[1] = o1;
    }
}

extern "C" void kernel_launch(void* const* d_in, const int* in_sizes, int n_in,
                              void* d_out, int out_size, void* d_ws, size_t ws_size,
                              hipStream_t stream) {
    const float* cons_x     = (const float*)d_in[0];
    const float* var_x      = (const float*)d_in[1];
    const int*   eidx       = (const int*)d_in[3];
    const float* cons_shift = (const float*)d_in[4];
    const float* cons_scale = (const float*)d_in[5];
    const float* cons_w1    = (const float*)d_in[6];
    const float* cons_b1    = (const float*)d_in[7];
    const float* cons_w2    = (const float*)d_in[8];
    const float* cons_b2    = (const float*)d_in[9];
    const float* var_shift  = (const float*)d_in[10];
    const float* var_scale  = (const float*)d_in[11];
    const float* var_w1     = (const float*)d_in[12];
    const float* var_b1     = (const float*)d_in[13];
    const float* var_w2     = (const float*)d_in[14];
    const float* var_b2     = (const float*)d_in[15];
    const float* ll_w       = (const float*)d_in[18];
    const float* ll_b       = (const float*)d_in[19];
    const float* lr_w       = (const float*)d_in[20];

    const int nC = in_sizes[0] / 5;
    const int nV = in_sizes[1] / 19;
    const int E  = in_sizes[3] / 2;
    const int* src = eidx;       // constraint ids
    const int* dst = eidx + E;   // variable ids

    int shc = 0; while ((nC >> shc) >= 512) ++shc;
    int shv = 0; while ((nV >> shv) >= 512) ++shv;
    const int NBC = (nC + (1 << shc) - 1) >> shc;
    const int NBV = (nV + (1 << shv) - 1) >> shv;

    char* w = (char*)d_ws;
    auto alloc = [&](size_t bytes) {
        char* p = w;
        w += (bytes + 255) & ~(size_t)255;
        return p;
    };
    float* x_c = (float*)alloc((size_t)nC * EMB * 4);   // u_c, then xhat_c
    float* x_v = (float*)alloc((size_t)nV * EMB * 4);   // u_v, then xhat_v
    float* t_c = (float*)alloc((size_t)nC * EMB * 4);   // aliases: slotted tmp_c, then bf16 tb_c
    float* t_v = (float*)alloc((size_t)nV * EMB * 4);
    unsigned* tmp_c = (unsigned*)t_c;
    unsigned* tmp_v = (unsigned*)t_v;
    unsigned short* tb_c = (unsigned short*)t_c;
    unsigned short* tb_v = (unsigned short*)t_v;
    int* rp_v  = (int*)alloc((size_t)(nV + 1) * 4);
    int* rp_c  = (int*)alloc((size_t)(nC + 1) * 4);
    int* adj_v = (int*)alloc((size_t)E * 4);
    int* adj_c = (int*)alloc((size_t)E * 4);
    int* bkt   = (int*)alloc(2048 * 4);
    int* gcur_c = bkt;            // counts, then exclusive bases (NBC+1)
    int* gcur_v = bkt + 1024;     // counts, then exclusive bases (NBV+1)

    // fixed per-bucket slots in tmp (2x mean, clamped to region capacity)
    auto slot_for = [&](int NB, size_t cap_ints) {
        long s = 2L * E / NB;
        s = (s + 255) & ~255L;
        if (s < 4096) s = 4096;
        long cap = (long)(cap_ints / NB) & ~255L;
        if (s > cap) s = cap;
        return (int)s;
    };
    const int SLOTC = slot_for(NBC, (size_t)nC * EMB);
    const int SLOTV = slot_for(NBV, (size_t)nV * EMB);

    auto llw = [&](int l, int d) { return ll_w + (size_t)(l * 2 + d) * EMB * EMB; };
    auto lrw = [&](int l, int d) { return lr_w + (size_t)(l * 2 + d) * EMB * EMB; };
    auto llb = [&](int l, int d) { return ll_b + (size_t)(l * 2 + d) * EMB; };

    // ---- CSR build (no histogram pass: fixed slots + post-scan) ----
    zero_int_kernel<<<8, 256, 0, stream>>>(bkt, 2048);
    bin_edges_kernel<<<(E + CH - 1) / CH, 256, 0, stream>>>(src, dst, E, gcur_c, gcur_v,
                                                            tmp_c, tmp_v, shc, shv, NBC, NBV,
                                                            SLOTC, SLOTV);
    scan_buckets_kernel<<<1, 256, 0, stream>>>(gcur_c, NBC, gcur_v, NBV, E);
    regroup2_dual_kernel<<<NBV + NBC, 256, 0, stream>>>(
        tmp_v, gcur_v, rp_v, adj_v, nV, shv, NBV, SLOTV,
        tmp_c, gcur_c, rp_c, adj_c, nC, shc, NBC, SLOTC, E);

    // ---- fused embed + layer-0 GEMMs, both sides in one dispatch ----
    int gc = (nC + 63) / 64, gv = (nV + 63) / 64;
    embed_dual_kernel<5, 19><<<gc + gv, 256, 0, stream>>>(
        cons_x, cons_shift, cons_scale, cons_w1, cons_b1, cons_w2, cons_b2,
        llw(0, 0), lrw(0, 1), tb_c, x_c, nC,
        var_x, var_shift, var_scale, var_w1, var_b1, var_w2, var_b2,
        llw(0, 1), lrw(0, 0), tb_v, x_v, nV,
        gc);

    // ---- layer-0 aggs (RMW u -> xhat), SEQUENTIAL (L2 working-set) ----
    int gv16 = (nV + 15) / 16, gc16 = (nC + 15) / 16;
    agg_rmw_kernel<<<gv16, 256, 0, stream>>>(tb_c, rp_v, adj_v, llb(0, 0), x_v, nV);
    agg_rmw_kernel<<<gc16, 256, 0, stream>>>(tb_v, rp_c, adj_c, llb(0, 1), x_c, nC);

    // ---- layer-1 GEMMs, one dispatch ----
    gemm64_dual_kernel<<<gc + gv, 256, 0, stream>>>(
        x_c, nC, llw(1, 0), tb_c,
        x_v, nV, lrw(1, 0), (float*)d_out, gc);

    // ---- final layer-1 var agg (RMW d_out) ----
    agg_rmw_kernel<<<gv16, 256, 0, stream>>>(tb_c, rp_v, adj_v, llb(1, 0), (float*)d_out, nV);
}